// Round 12
// baseline (1764.572 us; speedup 1.0000x reference)
//
#include <hip/hip_runtime.h>
#include <stdint.h>

typedef unsigned short u16;
typedef unsigned int   u32;
typedef __attribute__((ext_vector_type(8))) short bf16x8;
typedef __attribute__((ext_vector_type(4))) float f32x4;

#define NN    30000
#define NNP   30208   // NN padded to 256 for the 256-row GEMM tile
#define EFULL 240000
#define EPAR  30000

__device__ __forceinline__ float b2f(u16 u){ u32 x=((u32)u)<<16; float f; __builtin_memcpy(&f,&x,4); return f; }
__device__ __forceinline__ u16 f2b(float f){ u32 x; __builtin_memcpy(&x,&f,4); x += 0x7fffu + ((x>>16)&1u); return (u16)(x>>16); }

__device__ __forceinline__ void gload_lds16(const u16* g, u16* l){
  __builtin_amdgcn_global_load_lds((const __attribute__((address_space(1))) void*)g,
                                   (__attribute__((address_space(3))) void*)l, 16, 0, 0);
}

// ---------------- sentinel: workspace too small ----------------
__global__ void k_fail(float* out){ int t=threadIdx.x; if(t<128) out[t]=2.0f; }

// ---------------- batched edge-CSR build (z = graph: 0 full, 1 p1, 2 p2) ----------------
__global__ void k_counte3(const int* __restrict__ d0, const int* __restrict__ d1, const int* __restrict__ d2,
                          int* __restrict__ c0, int* __restrict__ c1, int* __restrict__ c2){
  int z = blockIdx.z;
  const int* d = z==0? d0 : z==1? d1 : d2;
  int* c = z==0? c0 : z==1? c1 : c2;
  int E = z==0? EFULL : EPAR;
  int e = blockIdx.x*256 + threadIdx.x;
  if (e < E) atomicAdd(&c[d[e]], 1);
}

__global__ void k_scan3(const int* __restrict__ c0, const int* __restrict__ c1, const int* __restrict__ c2,
                        int* __restrict__ r0, int* __restrict__ r1, int* __restrict__ r2,
                        int* __restrict__ w0, int* __restrict__ w1, int* __restrict__ w2){
  __shared__ int sums[1024];
  int z = blockIdx.x;
  const int* cnt = z==0? c0 : z==1? c1 : c2;
  int* rp = z==0? r0 : z==1? r1 : r2;
  int* wp = z==0? w0 : z==1? w1 : w2;
  int t = threadIdx.x;
  const int CH = (NN + 1023)/1024; // 30
  int c00 = t*CH;
  int s = 0;
  for (int i=0;i<CH;i++){ int idx=c00+i; s += (idx<NN)? cnt[idx] : 0; }
  sums[t] = s; __syncthreads();
  for (int off=1; off<1024; off<<=1){
    int v = (t>=off)? sums[t-off] : 0;
    __syncthreads();
    sums[t] += v;
    __syncthreads();
  }
  int run = (t==0)? 0 : sums[t-1];
  for (int i=0;i<CH;i++){
    int idx=c00+i;
    if (idx<NN){ rp[idx]=run; wp[idx]=run; run += cnt[idx]; }
  }
  if (t==1023) rp[NN] = sums[1023];
}

__global__ void k_fill3(const int* __restrict__ d0, const int* __restrict__ d1, const int* __restrict__ d2,
                        int* __restrict__ w0, int* __restrict__ w1, int* __restrict__ w2,
                        int* __restrict__ x0, int* __restrict__ x1, int* __restrict__ x2){
  int z = blockIdx.z;
  const int* d = z==0? d0 : z==1? d1 : d2;
  int* w = z==0? w0 : z==1? w1 : w2;
  int* x = z==0? x0 : z==1? x1 : x2;
  int E = z==0? EFULL : EPAR;
  int e = blockIdx.x*256 + threadIdx.x;
  if (e < E){ int p = atomicAdd(&w[d[e]], 1); x[p] = e; }
}

// ---------------- batched 64-bin counts (z: 0/1 route nodes, 2/3 route-of-dst edges) ----------------
__global__ void k_count64(const int* __restrict__ rt0, const int* __restrict__ rt1,
                          const int* __restrict__ d0, const int* __restrict__ d1,
                          int* __restrict__ c0, int* __restrict__ c1,
                          int* __restrict__ c2, int* __restrict__ c3){
  int z = blockIdx.z;
  int i = blockIdx.x*256 + threadIdx.x;
  if (i >= NN) return;  // NN == EPAR
  if      (z==0) atomicAdd(&c0[rt0[i]], 1);
  else if (z==1) atomicAdd(&c1[rt1[i]], 1);
  else if (z==2) atomicAdd(&c2[rt0[d0[i]]], 1);
  else           atomicAdd(&c3[rt1[d1[i]]], 1);
}

__global__ void k_scan64x4(const int* __restrict__ c0, const int* __restrict__ c1,
                           const int* __restrict__ c2, const int* __restrict__ c3,
                           int* __restrict__ r0, int* __restrict__ r1,
                           int* __restrict__ r2, int* __restrict__ r3,
                           int* __restrict__ w2, int* __restrict__ w3){
  int t = threadIdx.x;
  if (t >= 4) return;
  const int* c = t==0?c0:t==1?c1:t==2?c2:c3;
  int* r = t==0?r0:t==1?r1:t==2?r2:r3;
  int run=0;
  for (int i=0;i<64;i++){
    r[i]=run;
    if (t==2) w2[i]=run;
    if (t==3) w3[i]=run;
    run+=c[i];
  }
  r[64]=run;
}

__global__ void k_fille2(const int* __restrict__ rt0, const int* __restrict__ rt1,
                         const int* __restrict__ d0, const int* __restrict__ d1,
                         int* __restrict__ w2, int* __restrict__ w3,
                         int* __restrict__ x2, int* __restrict__ x3){
  int z = blockIdx.z;
  int i = blockIdx.x*256 + threadIdx.x;
  if (i >= EPAR) return;
  if (z==0){ int p=atomicAdd(&w2[rt0[d0[i]]],1);  x2[p]=i; }
  else     { int p=atomicAdd(&w3[rt1[d1[i]]],1);  x3[p]=i; }
}

// ---------------- per-route count of nodes with in-degree > 0 (z = parent) ----------------
__global__ void k_nre(const int* __restrict__ rp1, const int* __restrict__ rp2,
                      const int* __restrict__ rt1, const int* __restrict__ rt2,
                      int* __restrict__ n1, int* __restrict__ n2){
  int z = blockIdx.z;
  int n = blockIdx.x*256 + threadIdx.x;
  if (n >= NN) return;
  if (z==0){ if (rp1[n+1] > rp1[n]) atomicAdd(&n1[rt1[n]], 1); }
  else     { if (rp2[n+1] > rp2[n]) atomicAdd(&n2[rt2[n]], 1); }
}

// ---------------- layer-1 xl = x@Wl only (F=16 -> 512), bf16 out ----------------
__global__ __launch_bounds__(256) void k_xwl(const float* __restrict__ x,
                                             const float* __restrict__ Wl, u16* __restrict__ xl){
  int n = blockIdx.x;
  int c = blockIdx.y*256 + threadIdx.x;
  float a=0.f;
  #pragma unroll
  for (int k=0;k<16;k++) a += x[n*16+k]*Wl[k*512+c];
  xl[(size_t)n*512+c]=f2b(a);
}

// ---------------- fused layer-1 GAT: xr on-the-fly + logits+softmax+aggregate ----------------
__global__ __launch_bounds__(256) void k_gat1f(const int* __restrict__ ei,
    const float* __restrict__ ea,
    const int* __restrict__ rp, const int* __restrict__ eix,
    const float* __restrict__ x, const float* __restrict__ Wr,
    const float* __restrict__ We, const float* __restrict__ att,
    const u16* __restrict__ xl,
    const float* __restrict__ bias, u16* __restrict__ out){
  int lane = threadIdx.x & 63;
  int n = blockIdx.x*4 + (threadIdx.x>>6);
  if (n >= NN) return;
  int j0 = lane*8;
  float xv[16];
  #pragma unroll
  for (int k=0;k<16;k++) xv[k] = x[n*16+k];
  float we8[8], at8[8], rv8[8];
  #pragma unroll
  for (int j=0;j<8;j++){
    we8[j]=We[j0+j]; at8[j]=att[j0+j];
    float s=0.f;
    #pragma unroll
    for (int k=0;k<16;k++) s += xv[k]*Wr[k*512 + j0 + j];
    rv8[j]=s;
  }
  int r0 = rp[n], r1 = rp[n+1];
  float den = 0.f;
  float acc[8] = {0,0,0,0,0,0,0,0};
  for (int i=r0;i<r1;i++){
    int e = eix[i];
    int src = ei[e];
    float eaw = ea[e];
    bf16x8 lv = *(const bf16x8*)(xl + (size_t)src*512 + j0);
    float lvf[8];
    float logit = 0.f;
    #pragma unroll
    for (int j=0;j<8;j++){
      lvf[j] = b2f((u16)lv[j]);
      float v = lvf[j] + rv8[j] + eaw*we8[j];
      v = v>0.f? v : 0.2f*v;
      logit += v*at8[j];
    }
    logit += __shfl_xor(logit,1);
    logit += __shfl_xor(logit,2);
    logit += __shfl_xor(logit,4);
    float a = __expf(logit);
    den += a;
    #pragma unroll
    for (int j=0;j<8;j++) acc[j] += a*lvf[j];
  }
  float inv = 1.f/(den + 1e-16f);
  #pragma unroll
  for (int j=0;j<8;j++) out[(size_t)n*512 + j0 + j] = f2b(acc[j]*inv + bias[j0+j]);
}

// ---------------- BN stats, batched z=3, coalesced row-band ----------------
__global__ __launch_bounds__(256) void k_bnstats(const u16* __restrict__ P1, const u16* __restrict__ P2,
    const u16* __restrict__ PF, float* __restrict__ s1, float* __restrict__ s2, float* __restrict__ sF){
  int z = blockIdx.y;
  const u16* P = z==0? P1 : z==1? P2 : PF;
  float* st = z==0? s1 : z==1? s2 : sF;
  int t = threadIdx.x;
  const u32* Pu = (const u32*)P;
  int r0 = blockIdx.x*250, r1 = r0+250;
  float a0=0.f,a1=0.f,q0=0.f,q1=0.f;
  for (int r=r0;r<r1;r++){
    u32 v = Pu[(size_t)r*256 + t];
    float a = b2f((u16)(v & 0xffffu));
    float b = b2f((u16)(v >> 16));
    a0+=a; q0+=a*a; a1+=b; q1+=b*b;
  }
  atomicAdd(&st[2*t],       a0);
  atomicAdd(&st[2*t+1],     a1);
  atomicAdd(&st[512+2*t],   q0);
  atomicAdd(&st[512+2*t+1], q1);
}

// ---------------- BN fold prep: per-parent scale/shift over A's 1024 k-columns ----------------
__global__ void k_prep(const float* __restrict__ st1, const float* __restrict__ st2,
                       const float* __restrict__ stF,
                       const float* __restrict__ g, const float* __restrict__ b,
                       float* __restrict__ sc1, float* __restrict__ sh1,
                       float* __restrict__ sc2, float* __restrict__ sh2){
  int k = blockIdx.x*256 + threadIdx.x;
  if (k >= 1024) return;
  const float invN = 1.f/30000.f;
  const float* st = (k<512)? st1 : stF;
  int kk = k & 511;
  float mu = st[kk]*invN;
  float var = st[512+kk]*invN - mu*mu;
  float sc = g[k]*rsqrtf(var + 1e-5f);
  sc1[k] = sc; sh1[k] = b[k] - mu*sc;
  st = (k<512)? st2 : stF;
  mu = st[kk]*invN;
  var = st[512+kk]*invN - mu*mu;
  sc = g[k]*rsqrtf(var + 1e-5f);
  sc2[k] = sc; sh2[k] = b[k] - mu*sc;
}

// ---------------- B pre-transpose + scale + bf16: Bt_p[2048][1024] ----------------
__global__ __launch_bounds__(256) void k_bt(const float* __restrict__ B0, const float* __restrict__ B1,
                                            const float* __restrict__ sc1, const float* __restrict__ sc2,
                                            u16* __restrict__ Bt1, u16* __restrict__ Bt2){
  __shared__ float tile[64][65];
  int bk = blockIdx.x;
  int bn = blockIdx.y;
  int par = blockIdx.z>>1, half = blockIdx.z&1;
  const float* B = half ? B1 : B0;
  const float* sc = par ? sc2 : sc1;
  u16* Bt = par ? Bt2 : Bt1;
  int nb = half*1024;
  for (int i = threadIdx.x; i < 64*64; i += 256){
    int r = i>>6, c = i&63;
    tile[c][r] = B[(size_t)(bk*64+r)*1024 + bn*64 + c] * sc[bk*64+r];
  }
  __syncthreads();
  for (int i = threadIdx.x; i < 64*64; i += 256){
    int r = i>>6, c = i&63;
    Bt[(size_t)(nb + bn*64 + r)*1024 + bk*64 + c] = f2b(tile[r][c]);
  }
}

// ---------------- shiftB[n] = sum_k shift[k]*B[k][n], per parent ----------------
__global__ void k_shiftb(const float* __restrict__ B0, const float* __restrict__ B1,
                         const float* __restrict__ sh1, const float* __restrict__ sh2,
                         float* __restrict__ sb1, float* __restrict__ sb2){
  int c = blockIdx.x*256 + threadIdx.x;  // 0..2047
  const float* sh = blockIdx.y ? sh2 : sh1;
  float* sb = blockIdx.y ? sb2 : sb1;
  const float* B = (c < 1024) ? B0 : B1;
  int cc = c & 1023;
  float s = 0.f;
  for (int k=0;k<1024;k++) s += sh[k]*B[(size_t)k*1024 + cc];
  sb[c] = s;
}

// ---------------- 8-phase MFMA GEMM: CAT = [A0|A1]@Bt^T, bf16 out ----------------
// 256x256 tile, BK=64, 8 waves (2Mx4N), dbuf LDS 128KiB, counted vmcnt, setprio.
__global__ __launch_bounds__(512) void k_gemm8(const u16* __restrict__ A0, const u16* __restrict__ A1,
    const u16* __restrict__ Bt, u16* __restrict__ C, int M){
  __shared__ u16 Asm[2][256*64];
  __shared__ u16 Bsm[2][256*64];
  // grid (8, 118) = 944 = 8 XCDs x 118, bijective swizzle
  int lin = blockIdx.y*8 + blockIdx.x;
  int wg  = (lin&7)*118 + (lin>>3);
  int n0 = (wg & 7)*256;
  int m0 = (wg >> 3)*256;
  int t = threadIdx.x;
  int wave = t>>6, lane = t&63;
  int wm = (wave>>2)*128;       // 0 or 128
  int wn = (wave&3)*64;         // 0,64,128,192
  int rr = lane&15;
  int kq = lane>>4;             // 0..3
  int srow = t>>3;              // 0..63 (slab-local row)
  int schunk = t&7;
  int ssw = schunk ^ (srow&7);  // swizzled global source chunk (slabs are 64-row aligned)

  f32x4 acc[8][4];
  #pragma unroll
  for (int m=0;m<8;m++)
    #pragma unroll
    for (int n=0;n<4;n++){ acc[m][n][0]=0.f; acc[m][n][1]=0.f; acc[m][n][2]=0.f; acc[m][n][3]=0.f; }

  auto stageA = [&](int db, int kt, int R0){
    const u16* Ap = (kt < 8) ? A0 : A1;
    int kc = (kt & 7)*64;
    int row = R0 + srow;
    gload_lds16(Ap + (size_t)(m0+row)*512 + kc + ssw*8, &Asm[db][row*64 + schunk*8]);
  };
  auto stageB = [&](int db, int kt, int R0){
    int row = R0 + srow;
    gload_lds16(Bt + (size_t)(n0+row)*1024 + kt*64 + ssw*8, &Bsm[db][row*64 + schunk*8]);
  };
  auto rdA = [&](int db, int m, int ks)->bf16x8{
    int row = wm + m*16 + rr;
    int pc = (ks*4 + kq) ^ (row & 7);
    return *(const bf16x8*)(&Asm[db][row*64 + pc*8]);
  };
  auto rdB = [&](int db, int n, int ks)->bf16x8{
    int row = wn + n*16 + rr;
    int pc = (ks*4 + kq) ^ (row & 7);
    return *(const bf16x8*)(&Bsm[db][row*64 + pc*8]);
  };

  // prologue: stage tile 0 into buf 0.  Order: B (4 slabs), A-low (q0/q1 rows), A-high (q2/q3 rows)
  stageB(0,0,0); stageB(0,0,64); stageB(0,0,128); stageB(0,0,192);
  stageA(0,0,0); stageA(0,0,128);
  stageA(0,0,64); stageA(0,0,192);

  const int NT = 16;
  for (int kt=0; kt<NT; ++kt){
    int db = kt & 1, nb = db ^ 1;
    bool more = (kt < NT-1);
    // boundary: B + A-low of this tile done; A-high (2 newest) may be pending
    asm volatile("s_waitcnt vmcnt(2)" ::: "memory");
    __builtin_amdgcn_s_barrier();
    __builtin_amdgcn_sched_barrier(0);

    // ---- ph0: stage B[0:128) of kt+1; read B frags + A q0; MFMA q0
    if (more){ stageB(nb, kt+1, 0); stageB(nb, kt+1, 64); }
    bf16x8 bb[2][4];
    #pragma unroll
    for (int ks=0;ks<2;ks++)
      #pragma unroll
      for (int n=0;n<4;n++) bb[ks][n] = rdB(db, n, ks);
    {
      bf16x8 af[2][2];
      #pragma unroll
      for (int mi=0;mi<2;mi++)
        #pragma unroll
        for (int ks=0;ks<2;ks++) af[mi][ks] = rdA(db, mi, ks);
      __builtin_amdgcn_s_setprio(1);
      #pragma unroll
      for (int mi=0;mi<2;mi++)
        #pragma unroll
        for (int n=0;n<4;n++){
          acc[mi][n] = __builtin_amdgcn_mfma_f32_16x16x32_bf16(af[mi][0], bb[0][n], acc[mi][n], 0,0,0);
          acc[mi][n] = __builtin_amdgcn_mfma_f32_16x16x32_bf16(af[mi][1], bb[1][n], acc[mi][n], 0,0,0);
        }
      __builtin_amdgcn_s_setprio(0);
    }
    // ---- ph1: stage B[128:256) of kt+1; A q1; MFMA q1
    if (more){ stageB(nb, kt+1, 128); stageB(nb, kt+1, 192); }
    {
      bf16x8 af[2][2];
      #pragma unroll
      for (int mi=0;mi<2;mi++)
        #pragma unroll
        for (int ks=0;ks<2;ks++) af[mi][ks] = rdA(db, 2+mi, ks);
      __builtin_amdgcn_s_setprio(1);
      #pragma unroll
      for (int mi=0;mi<2;mi++)
        #pragma unroll
        for (int n=0;n<4;n++){
          acc[2+mi][n] = __builtin_amdgcn_mfma_f32_16x16x32_bf16(af[mi][0], bb[0][n], acc[2+mi][n], 0,0,0);
          acc[2+mi][n] = __builtin_amdgcn_mfma_f32_16x16x32_bf16(af[mi][1], bb[1][n], acc[2+mi][n], 0,0,0);
        }
      __builtin_amdgcn_s_setprio(0);
    }
    // ---- mid wait: drain this tile's A-high (pending allowed: ph0/ph1 B stages of kt+1)
    if (kt == NT-1) asm volatile("s_waitcnt vmcnt(0)" ::: "memory");
    else            asm volatile("s_waitcnt vmcnt(4)" ::: "memory");
    __builtin_amdgcn_s_barrier();
    __builtin_amdgcn_sched_barrier(0);

    // ---- ph2: stage A-low of kt+1; A q2; MFMA q2
    if (more){ stageA(nb, kt+1, 0); stageA(nb, kt+1, 128); }
    {
      bf16x8 af[2][2];
      #pragma unroll
      for (int mi=0;mi<2;mi++)
        #pragma unroll
        for (int ks=0;ks<2;ks++) af[mi][ks] = rdA(db, 4+mi, ks);
      __builtin_amdgcn_s_setprio(1);
      #pragma unroll
      for (int mi=0;mi<2;mi++)
        #pragma unroll
        for (int n=0;n<4;n++){
          acc[4+mi][n] = __builtin_amdgcn_mfma_f32_16x16x32_bf16(af[mi][0], bb[0][n], acc[4+mi][n], 0,0,0);
          acc[4+mi][n] = __builtin_amdgcn_mfma_f32_16x16x32_bf16(af[mi][1], bb[1][n], acc[4+mi][n], 0,0,0);
        }
      __builtin_amdgcn_s_setprio(0);
    }
    // ---- ph3: stage A-high of kt+1; A q3; MFMA q3
    if (more){ stageA(nb, kt+1, 64); stageA(nb, kt+1, 192); }
    {
      bf16x8 af[2][2];
      #pragma unroll
      for (int mi=0;mi<2;mi++)
        #pragma unroll
        for (int ks=0;ks<2;ks++) af[mi][ks] = rdA(db, 6+mi, ks);
      __builtin_amdgcn_s_setprio(1);
      #pragma unroll
      for (int mi=0;mi<2;mi++)
        #pragma unroll
        for (int n=0;n<4;n++){
          acc[6+mi][n] = __builtin_amdgcn_mfma_f32_16x16x32_bf16(af[mi][0], bb[0][n], acc[6+mi][n], 0,0,0);
          acc[6+mi][n] = __builtin_amdgcn_mfma_f32_16x16x32_bf16(af[mi][1], bb[1][n], acc[6+mi][n], 0,0,0);
        }
      __builtin_amdgcn_s_setprio(0);
    }
  }

  int rq = (lane>>4)*4;
  #pragma unroll
  for (int m=0;m<8;m++)
    #pragma unroll
    for (int n=0;n<4;n++)
      #pragma unroll
      for (int j=0;j<4;j++){
        int row = m0 + wm + m*16 + rq + j;
        int col = n0 + wn + n*16 + rr;
        if (row < M) C[(size_t)row*2048 + col] = f2b(acc[m][n][j]);
      }
}

// ---------------- node-centric layer-2 edge pass (sb folded into rv) ----------------
__global__ __launch_bounds__(256) void k_edge2f(const int* __restrict__ ei,
    const float* __restrict__ ea,
    const int* __restrict__ rp, const int* __restrict__ eix,
    const float* __restrict__ We, const float* __restrict__ att,
    const u16* __restrict__ CAT, const float* __restrict__ sb,
    float* __restrict__ alpha){
  int lane = threadIdx.x & 63;
  int n = blockIdx.x*4 + (threadIdx.x>>6);
  if (n >= NN) return;
  int j0 = lane*16;
  float rv[16], we16[16], at16[16];
  bf16x8 rr0 = *(const bf16x8*)(CAT + (size_t)n*2048 + 1024 + j0);
  bf16x8 rr1 = *(const bf16x8*)(CAT + (size_t)n*2048 + 1024 + j0 + 8);
  #pragma unroll
  for (int j=0;j<16;j++){
    rv[j] = b2f((u16)((j<8)? rr0[j] : rr1[j-8])) + sb[1024+j0+j] + sb[j0+j];
    we16[j]=We[j0+j]; at16[j]=att[j0+j];
  }
  int e0 = rp[n], e1 = rp[n+1];
  float den = 0.f;
  for (int i=e0;i<e1;i++){
    int e = eix[i];
    int src = ei[e];
    float eaw = ea[e];
    bf16x8 l0 = *(const bf16x8*)(CAT + (size_t)src*2048 + j0);
    bf16x8 l1 = *(const bf16x8*)(CAT + (size_t)src*2048 + j0 + 8);
    float logit = 0.f;
    #pragma unroll
    for (int j=0;j<16;j++){
      float v = b2f((u16)((j<8)? l0[j] : l1[j-8])) + rv[j] + eaw*we16[j];
      v = v>0.f? v : 0.2f*v;
      logit += v*at16[j];
    }
    logit += __shfl_xor(logit,1);
    logit += __shfl_xor(logit,2);
    logit += __shfl_xor(logit,4);
    float ex_ = __expf(logit);
    if ((lane&7)==0){ alpha[(size_t)e*8 + (lane>>3)] = ex_; den += ex_; }
  }
  float dh = __shfl(den, (lane&7)*8);
  float inv = 1.f/(dh + 1e-16f);
  if (lane < 8){
    for (int i=e0;i<e1;i++){
      int e = eix[i];
      alpha[(size_t)e*8 + lane] *= inv;
    }
  }
}

// ---------------- fused layer-2 aggregation + route pooling (edge-centric) ----------------
#define ECH 32
__global__ __launch_bounds__(256) void k_agg2pool(const int* __restrict__ ei,
    const int* __restrict__ rerp, const int* __restrict__ reix,
    const int* __restrict__ rrp, const int* __restrict__ nre,
    const float* __restrict__ alpha, const u16* __restrict__ CAT,
    const float* __restrict__ b3, const float* __restrict__ sb,
    float* __restrict__ rs){
  int r = blockIdx.x;
  int c = blockIdx.z*256 + threadIdx.x;   // 0..1023
  int h = c >> 7;
  int i0 = rerp[r], i1 = rerp[r+1];
  int per = (i1 - i0 + ECH - 1)/ECH;
  int s0 = i0 + blockIdx.y*per;
  int s1 = min(i1, s0 + per);
  float acc = 0.f;
  for (int i=s0;i<s1;i++){
    int e = reix[i];
    float a = alpha[(size_t)e*8 + h];
    acc += a * b2f(CAT[(size_t)ei[e]*2048 + c]);
  }
  if (blockIdx.y == 0)
    acc += (float)(rrp[r+1]-rrp[r]) * b3[c] + (float)nre[r] * sb[c];
  if (s0 < s1 || blockIdx.y == 0) atomicAdd(&rs[r*1024 + c], acc);
}

// ---------------- fused cumsum over routes + pn BN -> H0 directly ----------------
__global__ void k_cumsum_bn(const float* __restrict__ rs1, const float* __restrict__ rs2,
                            const float* __restrict__ g, const float* __restrict__ b,
                            float* __restrict__ h){
  const float* rs = blockIdx.y ? rs2 : rs1;
  int colbase = blockIdx.y ? 2048 : 0;
  int c = blockIdx.x*256 + threadIdx.x; // 0..1023
  float tot = 0.f;
  for (int r=0;r<64;r++) tot += rs[r*1024+c];
  float cs=0.f, s0=0.f,q0=0.f,s1=0.f,q1=0.f;
  for (int r=0;r<64;r++){
    cs += rs[r*1024+c];
    float m = tot - cs;
    s0+=cs; q0+=cs*cs; s1+=m; q1+=m*m;
  }
  float mu0=s0*(1.f/64.f), v0=q0*(1.f/64.f)-mu0*mu0, n0=rsqrtf(v0+1e-5f);
  float mu1=s1*(1.f/64.f), v1=q1*(1.f/64.f)-mu1*mu1, n1=rsqrtf(v1+1e-5f);
  float g0=g[colbase+c],      b0=b[colbase+c];
  float g1=g[colbase+1024+c], b1=b[colbase+1024+c];
  cs = 0.f;
  for (int r=0;r<64;r++){
    cs += rs[r*1024+c];
    float m = tot - cs;
    h[r*4096 + colbase + c]        = (cs-mu0)*n0*g0 + b0;
    h[r*4096 + colbase + 1024 + c] = (m -mu1)*n1*g1 + b1;
  }
}

// ---------------- MLP split-K partials: PART[sk][64][Co] ----------------
#define KC 512
__global__ __launch_bounds__(256) void k_mlp_part(const float* __restrict__ In,
    const float* __restrict__ W, float* __restrict__ PART, int Ci, int Co){
  __shared__ float tin[64*64];
  int c  = blockIdx.x*64 + (threadIdx.x&63);
  int rg = threadIdx.x>>6;
  int k0 = blockIdx.y*KC, k1 = min(Ci, k0+KC);
  float acc[16];
  #pragma unroll
  for (int j=0;j<16;j++) acc[j]=0.f;
  for (int ks=k0; ks<k1; ks+=64){
    int kw = min(64, k1-ks);
    __syncthreads();
    for (int i=threadIdx.x;i<64*64;i+=256){
      int r=i>>6, k=i&63;
      tin[i] = (k<kw)? In[(size_t)r*Ci + ks + k] : 0.f;
    }
    __syncthreads();
    if (c < Co){
      for (int k=0;k<kw;k+=4){
        float4 w4;
        w4.x = W[(size_t)(ks+k  )*Co + c];
        w4.y = W[(size_t)(ks+k+1)*Co + c];
        w4.z = W[(size_t)(ks+k+2)*Co + c];
        w4.w = W[(size_t)(ks+k+3)*Co + c];
        #pragma unroll
        for (int j=0;j<16;j++){
          float4 t4 = *(const float4*)(&tin[(rg*16+j)*64 + k]);
          acc[j] += t4.x*w4.x + t4.y*w4.y + t4.z*w4.z + t4.w*w4.w;
        }
      }
    }
  }
  if (c < Co){
    float* P = PART + (size_t)blockIdx.y*64*Co;
    #pragma unroll
    for (int j=0;j<16;j++)
      P[(size_t)(rg*16+j)*Co + c] = acc[j];
  }
}

// ---------------- MLP reduce: Out = act(sum_sk PART + bias) ----------------
__global__ void k_mlp_red(const float* __restrict__ PART, const float* __restrict__ bias,
                          float* __restrict__ Out, int Co, int SK, int act){
  int idx = blockIdx.x*256 + threadIdx.x;
  if (idx >= 64*Co) return;
  int c = idx % Co;
  float s = bias[c];
  for (int sk=0; sk<SK; sk++) s += PART[(size_t)sk*64*Co + idx];
  if (act) s = s>0.f ? s : 0.01f*s;
  Out[idx] = s;
}

// ---------------- fused MLP tail: 128 -> 64 -> 32 -> 1 + sigmoid ----------------
__global__ __launch_bounds__(256) void k_mlp_tail(const float* __restrict__ In,
    const float* __restrict__ W6, const float* __restrict__ c6,
    const float* __restrict__ W7, const float* __restrict__ c7,
    const float* __restrict__ W8, const float* __restrict__ c8,
    float* __restrict__ out){
  __shared__ float A[64*128];
  __shared__ float B[64*64];
  int t = threadIdx.x;
  for (int i=t;i<64*128;i+=256) A[i] = In[i];
  __syncthreads();
  for (int idx=t; idx<64*64; idx+=256){
    int r=idx>>6, c=idx&63;
    float s=c6[c];
    for (int k=0;k<128;k++) s += A[r*128+k]*W6[k*64+c];
    B[idx] = s>0.f? s : 0.01f*s;
  }
  __syncthreads();
  for (int idx=t; idx<64*32; idx+=256){
    int r=idx>>5, c=idx&31;
    float s=c7[c];
    for (int k=0;k<64;k++) s += B[r*64+k]*W7[k*32+c];
    A[idx] = s>0.f? s : 0.01f*s;
  }
  __syncthreads();
  if (t<64){
    float s=c8[0];
    for (int k=0;k<32;k++) s += A[t*32+k]*W8[k];
    out[t] = 1.f/(1.f + __expf(-s));
    out[64+t] = 0.f;
  }
}

extern "C" void kernel_launch(void* const* d_in, const int* in_sizes, int n_in,
                              void* d_out, int out_size, void* d_ws, size_t ws_size,
                              hipStream_t stream)
{
  const float* x_p1   = (const float*)d_in[0];
  const float* x_p2   = (const float*)d_in[1];
  const float* x_full = (const float*)d_in[2];
  const float* ea_p1  = (const float*)d_in[3];
  const float* ea_p2  = (const float*)d_in[4];
  const float* ea_full= (const float*)d_in[5];
  const int* ei_p1  = (const int*)d_in[6];
  const int* ei_p2  = (const int*)d_in[7];
  const int* ei_full= (const int*)d_in[8];
  const int* route_p1 = (const int*)d_in[9];
  const int* route_p2 = (const int*)d_in[10];
  const float *Wl1=(const float*)d_in[11], *Wr1=(const float*)d_in[12], *We1=(const float*)d_in[13], *att1=(const float*)d_in[14], *b1=(const float*)d_in[15];
  const float *Wl2=(const float*)d_in[16], *Wr2=(const float*)d_in[17], *We2=(const float*)d_in[18], *att2=(const float*)d_in[19], *b2=(const float*)d_in[20];
  const float *Wl3=(const float*)d_in[21], *Wr3=(const float*)d_in[22], *We3=(const float*)d_in[23], *att3=(const float*)d_in[24], *b3=(const float*)d_in[25];
  const float *bng=(const float*)d_in[26], *bnb=(const float*)d_in[27], *png=(const float*)d_in[28], *pnb=(const float*)d_in[29];
  const float *W[8], *Cb[8];
  for (int i=0;i<8;i++){ W[i]=(const float*)d_in[30+2*i]; Cb[i]=(const float*)d_in[31+2*i]; }

  char* w = (char*)d_ws;
  size_t off = 0;
  auto alloc = [&](size_t bytes)->char*{ char* p = w + off; off += (bytes + 255) & ~(size_t)255; return p; };
  u16* P1bf = (u16*)alloc((size_t)NNP*512*2);   // padded to 30208 rows for 256-row GEMM tiles
  u16* P2bf = (u16*)alloc((size_t)NNP*512*2);
  u16* FGbf = (u16*)alloc((size_t)NNP*512*2);
  char* BIG = alloc((size_t)NN*2048*2);           // phase1: XL  phase3: CAT
  u16*   XLbf = (u16*)BIG;
  u16*   CATbf= (u16*)BIG;
  u16*   Bt1  = (u16*)alloc((size_t)2048*1024*2);
  u16*   Bt2  = (u16*)alloc((size_t)2048*1024*2);
  float* ALPHA=(float*)alloc((size_t)EPAR*8*4);
  float* st1 = (float*)alloc(1024*4);
  float* st2 = (float*)alloc(1024*4);
  float* stF = (float*)alloc(1024*4);
  float* rs1 = (float*)alloc(64*1024*4);
  float* rs2 = (float*)alloc(64*1024*4);
  float* sc1 = (float*)alloc(1024*4);
  float* sh1 = (float*)alloc(1024*4);
  float* sc2 = (float*)alloc(1024*4);
  float* sh2 = (float*)alloc(1024*4);
  float* sb1 = (float*)alloc(2048*4);
  float* sb2 = (float*)alloc(2048*4);
  float* H0  = (float*)alloc(64*4096*4);
  float* H1  = (float*)alloc(64*4096*4);
  float* PART= (float*)alloc((size_t)8*64*2048*4);
  char* cnt_base = alloc(0);
  int* cntF = (int*)alloc(NN*4);
  int* cntA = (int*)alloc(NN*4);
  int* cntB = (int*)alloc(NN*4);
  int* c64a = (int*)alloc(64*4);
  int* c64b = (int*)alloc(64*4);
  int* c64c = (int*)alloc(64*4);
  int* c64d = (int*)alloc(64*4);
  int* nre1 = (int*)alloc(64*4);
  int* nre2 = (int*)alloc(64*4);
  size_t cnt_bytes = (size_t)((char*)alloc(0) - cnt_base);
  int* wpF = (int*)alloc(NN*4);
  int* wpA = (int*)alloc(NN*4);
  int* wpB = (int*)alloc(NN*4);
  int* w64c= (int*)alloc(64*4);
  int* w64d= (int*)alloc(64*4);
  int* rpF = (int*)alloc((NN+1)*4);
  int* rp1 = (int*)alloc((NN+1)*4);
  int* rp2 = (int*)alloc((NN+1)*4);
  int* eixF= (int*)alloc((size_t)EFULL*4);
  int* eix1= (int*)alloc((size_t)EPAR*4);
  int* eix2= (int*)alloc((size_t)EPAR*4);
  int* rr1 = (int*)alloc(65*4);
  int* rr2 = (int*)alloc(65*4);
  int* rerp1=(int*)alloc(65*4);
  int* rerp2=(int*)alloc(65*4);
  int* reix1=(int*)alloc((size_t)EPAR*4);
  int* reix2=(int*)alloc((size_t)EPAR*4);
  if (ws_size < off){ k_fail<<<1,128,0,stream>>>((float*)d_out); return; }

  // ---- zero counters (1 memset) + stats/rs (1 memset, contiguous st1..rs2) ----
  hipMemsetAsync(cnt_base, 0, cnt_bytes, stream);
  hipMemsetAsync(st1, 0, (size_t)((char*)rs2 - (char*)st1) + 64*1024*4, stream);

  // ---- batched CSR builds ----
  k_counte3<<<dim3((EFULL+255)/256,1,3), 256, 0, stream>>>(ei_full+EFULL, ei_p1+EPAR, ei_p2+EPAR,
                                                           cntF, cntA, cntB);
  k_scan3  <<<3, 1024, 0, stream>>>(cntF, cntA, cntB, rpF, rp1, rp2, wpF, wpA, wpB);
  k_fill3  <<<dim3((EFULL+255)/256,1,3), 256, 0, stream>>>(ei_full+EFULL, ei_p1+EPAR, ei_p2+EPAR,
                                                           wpF, wpA, wpB, eixF, eix1, eix2);
  k_count64<<<dim3((NN+255)/256,1,4), 256, 0, stream>>>(route_p1, route_p2, ei_p1+EPAR, ei_p2+EPAR,
                                                        c64a, c64b, c64c, c64d);
  k_scan64x4<<<1, 64, 0, stream>>>(c64a,c64b,c64c,c64d, rr1,rr2,rerp1,rerp2, w64c,w64d);
  k_fille2 <<<dim3((NN+255)/256,1,2), 256, 0, stream>>>(route_p1, route_p2, ei_p1+EPAR, ei_p2+EPAR,
                                                        w64c, w64d, reix1, reix2);
  k_nre    <<<dim3((NN+255)/256,1,2), 256, 0, stream>>>(rp1, rp2, route_p1, route_p2, nre1, nre2);

  // ---- layer-1 GAT (xl materialized, xr on-the-fly) ----
  auto gat1 = [&](const float* x, const int* ei, const float* ea, const int* rp, const int* eix,
                  const float* Wl, const float* Wr, const float* We, const float* att, const float* bias,
                  u16* out){
    k_xwl  <<<dim3(NN,2), 256, 0, stream>>>(x, Wl, XLbf);
    k_gat1f<<<(NN+3)/4, 256, 0, stream>>>(ei, ea, rp, eix, x, Wr, We, att, XLbf, bias, out);
  };
  gat1(x_full, ei_full, ea_full, rpF, eixF, Wl2, Wr2, We2, att2, b2, FGbf);
  gat1(x_p1,   ei_p1,   ea_p1,   rp1, eix1, Wl1, Wr1, We1, att1, b1, P1bf);
  gat1(x_p2,   ei_p2,   ea_p2,   rp2, eix2, Wl1, Wr1, We1, att1, b1, P2bf);

  // ---- BN stats + fold into GEMM B ----
  k_bnstats<<<dim3(120,3), 256, 0, stream>>>(P1bf, P2bf, FGbf, st1, st2, stF);
  k_prep   <<<4, 256, 0, stream>>>(st1, st2, stF, bng, bnb, sc1, sh1, sc2, sh2);
  k_bt     <<<dim3(16,16,4), 256, 0, stream>>>(Wl3, Wr3, sc1, sc2, Bt1, Bt2);
  k_shiftb <<<dim3(8,2), 256, 0, stream>>>(Wl3, Wr3, sh1, sh2, sb1, sb2);

  // ---- layer-2 GAT + fused route pooling, per parent ----
  auto layer2 = [&](const u16* Pbf, const u16* Bt, const float* sb,
                    const int* ei, const float* ea, const int* rp, const int* eix,
                    const int* rrp, const int* nre, const int* rerp, const int* reix, float* rs){
    k_gemm8 <<<dim3(8, 118), 512, 0, stream>>>(Pbf, FGbf, Bt, CATbf, NN);
    k_edge2f<<<(NN+3)/4, 256, 0, stream>>>(ei, ea, rp, eix, We3, att3, CATbf, sb, ALPHA);
    k_agg2pool<<<dim3(64,ECH,4), 256, 0, stream>>>(ei, rerp, reix, rrp, nre, ALPHA, CATbf, b3, sb, rs);
  };
  layer2(P1bf, Bt1, sb1, ei_p1, ea_p1, rp1, eix1, rr1, nre1, rerp1, reix1, rs1);
  layer2(P2bf, Bt2, sb2, ei_p2, ea_p2, rp2, eix2, rr2, nre2, rerp2, reix2, rs2);

  // ---- fused cumsum + pn BN -> H0 ----
  k_cumsum_bn<<<dim3(4,2), 256, 0, stream>>>(rs1, rs2, png, pnb, H0);

  // ---- MLP: layers 1-5 split-K, tail fused ----
  int dims[9] = {4096, 2048, 1024, 512, 256, 128, 64, 32, 1};
  float* bufs[2] = {H0, H1};
  for (int i=0;i<5;i++){
    int Ci = dims[i], Co = dims[i+1];
    int SK = (Ci + KC - 1)/KC;
    k_mlp_part<<<dim3((Co+63)/64, SK), 256, 0, stream>>>(bufs[i&1], W[i], PART, Ci, Co);
    k_mlp_red <<<(64*Co+255)/256, 256, 0, stream>>>(PART, Cb[i], bufs[(i+1)&1], Co, SK, 1);
  }
  k_mlp_tail<<<1, 256, 0, stream>>>(bufs[1], W[5], Cb[5], W[6], Cb[6], W[7], Cb[7], (float*)d_out);
}

// Round 13
// 1676.076 us; speedup vs baseline: 1.0528x; 1.0528x over previous
//
#include <hip/hip_runtime.h>
#include <stdint.h>

typedef unsigned short u16;
typedef unsigned int   u32;
typedef __attribute__((ext_vector_type(8))) short bf16x8;
typedef __attribute__((ext_vector_type(4))) float f32x4;

#define NN    30000
#define NNP   30208   // NN padded so unconditional 128-row GEMM tile loads stay in-bounds
#define EFULL 240000
#define EPAR  30000

__device__ __forceinline__ float b2f(u16 u){ u32 x=((u32)u)<<16; float f; __builtin_memcpy(&f,&x,4); return f; }
__device__ __forceinline__ u16 f2b(float f){ u32 x; __builtin_memcpy(&x,&f,4); x += 0x7fffu + ((x>>16)&1u); return (u16)(x>>16); }

__device__ __forceinline__ void gload_lds16(const u16* g, u16* l){
  __builtin_amdgcn_global_load_lds((const __attribute__((address_space(1))) void*)g,
                                   (__attribute__((address_space(3))) void*)l, 16, 0, 0);
}

// ---------------- sentinel: workspace too small ----------------
__global__ void k_fail(float* out){ int t=threadIdx.x; if(t<128) out[t]=2.0f; }

// ---------------- batched edge-CSR counts (z = graph: 0 full, 1 p1, 2 p2) ----------------
__global__ void k_counte3(const int* __restrict__ d0, const int* __restrict__ d1, const int* __restrict__ d2,
                          int* __restrict__ c0, int* __restrict__ c1, int* __restrict__ c2){
  int z = blockIdx.z;
  const int* d = z==0? d0 : z==1? d1 : d2;
  int* c = z==0? c0 : z==1? c1 : c2;
  int E = z==0? EFULL : EPAR;
  int e = blockIdx.x*256 + threadIdx.x;
  if (e < E) atomicAdd(&c[d[e]], 1);
}

__global__ void k_scan3(const int* __restrict__ c0, const int* __restrict__ c1, const int* __restrict__ c2,
                        int* __restrict__ r0, int* __restrict__ r1, int* __restrict__ r2,
                        int* __restrict__ w0, int* __restrict__ w1, int* __restrict__ w2){
  __shared__ int sums[1024];
  int z = blockIdx.x;
  const int* cnt = z==0? c0 : z==1? c1 : c2;
  int* rp = z==0? r0 : z==1? r1 : r2;
  int* wp = z==0? w0 : z==1? w1 : w2;
  int t = threadIdx.x;
  const int CH = (NN + 1023)/1024; // 30
  int c00 = t*CH;
  int s = 0;
  for (int i=0;i<CH;i++){ int idx=c00+i; s += (idx<NN)? cnt[idx] : 0; }
  sums[t] = s; __syncthreads();
  for (int off=1; off<1024; off<<=1){
    int v = (t>=off)? sums[t-off] : 0;
    __syncthreads();
    sums[t] += v;
    __syncthreads();
  }
  int run = (t==0)? 0 : sums[t-1];
  for (int i=0;i<CH;i++){
    int idx=c00+i;
    if (idx<NN){ rp[idx]=run; wp[idx]=run; run += cnt[idx]; }
  }
  if (t==1023) rp[NN] = sums[1023];
}

// ---------------- batched 64-bin counts (z: 0/1 route nodes, 2/3 route-of-dst edges) ----------------
__global__ void k_count64(const int* __restrict__ rt0, const int* __restrict__ rt1,
                          const int* __restrict__ d0, const int* __restrict__ d1,
                          int* __restrict__ c0, int* __restrict__ c1,
                          int* __restrict__ c2, int* __restrict__ c3){
  int z = blockIdx.z;
  int i = blockIdx.x*256 + threadIdx.x;
  if (i >= NN) return;  // NN == EPAR
  if      (z==0) atomicAdd(&c0[rt0[i]], 1);
  else if (z==1) atomicAdd(&c1[rt1[i]], 1);
  else if (z==2) atomicAdd(&c2[rt0[d0[i]]], 1);
  else           atomicAdd(&c3[rt1[d1[i]]], 1);
}

__global__ void k_scan64x4(const int* __restrict__ c0, const int* __restrict__ c1,
                           const int* __restrict__ c2, const int* __restrict__ c3,
                           int* __restrict__ r0, int* __restrict__ r1,
                           int* __restrict__ r2, int* __restrict__ r3,
                           int* __restrict__ w2, int* __restrict__ w3){
  int t = threadIdx.x;
  if (t >= 4) return;
  const int* c = t==0?c0:t==1?c1:t==2?c2:c3;
  int* r = t==0?r0:t==1?r1:t==2?r2:r3;
  int run=0;
  for (int i=0;i<64;i++){
    r[i]=run;
    if (t==2) w2[i]=run;
    if (t==3) w3[i]=run;
    run+=c[i];
  }
  r[64]=run;
}

// ---------------- merged fills: z=0..2 edge CSR, z=3..4 route-edge CSR, z=5..6 nre ----------------
__global__ void k_fill_all(
    const int* __restrict__ dF, const int* __restrict__ d1, const int* __restrict__ d2,
    int* __restrict__ wF, int* __restrict__ wA, int* __restrict__ wB,
    int* __restrict__ xF, int* __restrict__ x1, int* __restrict__ x2,
    const int* __restrict__ rt1, const int* __restrict__ rt2,
    int* __restrict__ w64c, int* __restrict__ w64d,
    int* __restrict__ reix1, int* __restrict__ reix2,
    const int* __restrict__ rp1, const int* __restrict__ rp2,
    int* __restrict__ nre1, int* __restrict__ nre2){
  int z = blockIdx.z;
  int i = blockIdx.x*256 + threadIdx.x;
  if      (z==0){ if (i<EFULL){ int p=atomicAdd(&wF[dF[i]],1);          xF[p]=i; } }
  else if (z==1){ if (i<EPAR) { int p=atomicAdd(&wA[d1[i]],1);          x1[p]=i; } }
  else if (z==2){ if (i<EPAR) { int p=atomicAdd(&wB[d2[i]],1);          x2[p]=i; } }
  else if (z==3){ if (i<EPAR) { int p=atomicAdd(&w64c[rt1[d1[i]]],1);   reix1[p]=i; } }
  else if (z==4){ if (i<EPAR) { int p=atomicAdd(&w64d[rt2[d2[i]]],1);   reix2[p]=i; } }
  else if (z==5){ if (i<NN && rp1[i+1]>rp1[i]) atomicAdd(&nre1[rt1[i]],1); }
  else          { if (i<NN && rp2[i+1]>rp2[i]) atomicAdd(&nre2[rt2[i]],1); }
}

// ---------------- layer-1 xl = x@Wl, batched over 3 graphs (z) ----------------
__global__ __launch_bounds__(256) void k_xwl3(const float* __restrict__ xf,
    const float* __restrict__ x1, const float* __restrict__ x2,
    const float* __restrict__ WlF, const float* __restrict__ WlP,
    u16* __restrict__ xlF, u16* __restrict__ xl1, u16* __restrict__ xl2){
  int z = blockIdx.z;
  const float* x = z==0? xf : z==1? x1 : x2;
  const float* Wl = z==0? WlF : WlP;
  u16* xl = z==0? xlF : z==1? xl1 : xl2;
  int n = blockIdx.x;
  int c = blockIdx.y*256 + threadIdx.x;
  float a=0.f;
  #pragma unroll
  for (int k=0;k<16;k++) a += x[n*16+k]*Wl[k*512+c];
  xl[(size_t)n*512+c]=f2b(a);
}

// ---------------- fused layer-1 GAT, batched over 3 graphs (z) ----------------
__global__ __launch_bounds__(256) void k_gat1f3(
    const int* __restrict__ eiF, const float* __restrict__ eaF,
    const int* __restrict__ rpF, const int* __restrict__ eixF,
    const float* __restrict__ xF, const float* __restrict__ WrF,
    const float* __restrict__ WeF, const float* __restrict__ attF,
    const u16* __restrict__ xlF, const float* __restrict__ bF, u16* __restrict__ outF,
    const int* __restrict__ ei1, const float* __restrict__ ea1,
    const int* __restrict__ rp1, const int* __restrict__ eix1,
    const float* __restrict__ x1p, const float* __restrict__ WrP,
    const float* __restrict__ WeP, const float* __restrict__ attP,
    const u16* __restrict__ xl1, const float* __restrict__ bP, u16* __restrict__ out1,
    const int* __restrict__ ei2, const float* __restrict__ ea2,
    const int* __restrict__ rp2, const int* __restrict__ eix2,
    const float* __restrict__ x2p, const u16* __restrict__ xl2, u16* __restrict__ out2){
  int z = blockIdx.z;
  const int* ei  = z==0? eiF : z==1? ei1 : ei2;
  const float* ea= z==0? eaF : z==1? ea1 : ea2;
  const int* rp  = z==0? rpF : z==1? rp1 : rp2;
  const int* eix = z==0? eixF: z==1? eix1: eix2;
  const float* x = z==0? xF  : z==1? x1p : x2p;
  const float* Wr= z==0? WrF : WrP;
  const float* We= z==0? WeF : WeP;
  const float* att=z==0? attF: attP;
  const u16* xl  = z==0? xlF : z==1? xl1 : xl2;
  const float* bias = z==0? bF : bP;
  u16* out = z==0? outF : z==1? out1 : out2;

  int lane = threadIdx.x & 63;
  int n = blockIdx.x*4 + (threadIdx.x>>6);
  if (n >= NN) return;
  int j0 = lane*8;
  float xv[16];
  #pragma unroll
  for (int k=0;k<16;k++) xv[k] = x[n*16+k];
  float we8[8], at8[8], rv8[8];
  #pragma unroll
  for (int j=0;j<8;j++){
    we8[j]=We[j0+j]; at8[j]=att[j0+j];
    float s=0.f;
    #pragma unroll
    for (int k=0;k<16;k++) s += xv[k]*Wr[k*512 + j0 + j];
    rv8[j]=s;
  }
  int r0 = rp[n], r1 = rp[n+1];
  float den = 0.f;
  float acc[8] = {0,0,0,0,0,0,0,0};
  for (int i=r0;i<r1;i++){
    int e = eix[i];
    int src = ei[e];
    float eaw = ea[e];
    bf16x8 lv = *(const bf16x8*)(xl + (size_t)src*512 + j0);
    float lvf[8];
    float logit = 0.f;
    #pragma unroll
    for (int j=0;j<8;j++){
      lvf[j] = b2f((u16)lv[j]);
      float v = lvf[j] + rv8[j] + eaw*we8[j];
      v = v>0.f? v : 0.2f*v;
      logit += v*at8[j];
    }
    logit += __shfl_xor(logit,1);
    logit += __shfl_xor(logit,2);
    logit += __shfl_xor(logit,4);
    float a = __expf(logit);
    den += a;
    #pragma unroll
    for (int j=0;j<8;j++) acc[j] += a*lvf[j];
  }
  float inv = 1.f/(den + 1e-16f);
  #pragma unroll
  for (int j=0;j<8;j++) out[(size_t)n*512 + j0 + j] = f2b(acc[j]*inv + bias[j0+j]);
}

// ---------------- BN stats, batched z=3, coalesced row-band ----------------
__global__ __launch_bounds__(256) void k_bnstats(const u16* __restrict__ P1, const u16* __restrict__ P2,
    const u16* __restrict__ PF, float* __restrict__ s1, float* __restrict__ s2, float* __restrict__ sF){
  int z = blockIdx.y;
  const u16* P = z==0? P1 : z==1? P2 : PF;
  float* st = z==0? s1 : z==1? s2 : sF;
  int t = threadIdx.x;
  const u32* Pu = (const u32*)P;
  int r0 = blockIdx.x*250, r1 = r0+250;
  float a0=0.f,a1=0.f,q0=0.f,q1=0.f;
  for (int r=r0;r<r1;r++){
    u32 v = Pu[(size_t)r*256 + t];
    float a = b2f((u16)(v & 0xffffu));
    float b = b2f((u16)(v >> 16));
    a0+=a; q0+=a*a; a1+=b; q1+=b*b;
  }
  atomicAdd(&st[2*t],       a0);
  atomicAdd(&st[2*t+1],     a1);
  atomicAdd(&st[512+2*t],   q0);
  atomicAdd(&st[512+2*t+1], q1);
}

// ---------------- BN fold prep: per-parent scale/shift over A's 1024 k-columns ----------------
__global__ void k_prep(const float* __restrict__ st1, const float* __restrict__ st2,
                       const float* __restrict__ stF,
                       const float* __restrict__ g, const float* __restrict__ b,
                       float* __restrict__ sc1, float* __restrict__ sh1,
                       float* __restrict__ sc2, float* __restrict__ sh2){
  int k = blockIdx.x*256 + threadIdx.x;
  if (k >= 1024) return;
  const float invN = 1.f/30000.f;
  const float* st = (k<512)? st1 : stF;
  int kk = k & 511;
  float mu = st[kk]*invN;
  float var = st[512+kk]*invN - mu*mu;
  float sc = g[k]*rsqrtf(var + 1e-5f);
  sc1[k] = sc; sh1[k] = b[k] - mu*sc;
  st = (k<512)? st2 : stF;
  mu = st[kk]*invN;
  var = st[512+kk]*invN - mu*mu;
  sc = g[k]*rsqrtf(var + 1e-5f);
  sc2[k] = sc; sh2[k] = b[k] - mu*sc;
}

// ---------------- B pre-transpose + scale + bf16: Bt_p[2048][1024] ----------------
__global__ __launch_bounds__(256) void k_bt(const float* __restrict__ B0, const float* __restrict__ B1,
                                            const float* __restrict__ sc1, const float* __restrict__ sc2,
                                            u16* __restrict__ Bt1, u16* __restrict__ Bt2){
  __shared__ float tile[64][65];
  int bk = blockIdx.x;
  int bn = blockIdx.y;
  int par = blockIdx.z>>1, half = blockIdx.z&1;
  const float* B = half ? B1 : B0;
  const float* sc = par ? sc2 : sc1;
  u16* Bt = par ? Bt2 : Bt1;
  int nb = half*1024;
  for (int i = threadIdx.x; i < 64*64; i += 256){
    int r = i>>6, c = i&63;
    tile[c][r] = B[(size_t)(bk*64+r)*1024 + bn*64 + c] * sc[bk*64+r];
  }
  __syncthreads();
  for (int i = threadIdx.x; i < 64*64; i += 256){
    int r = i>>6, c = i&63;
    Bt[(size_t)(nb + bn*64 + r)*1024 + bk*64 + c] = f2b(tile[r][c]);
  }
}

// ---------------- shiftB[n] = sum_k shift[k]*B[k][n], per parent ----------------
__global__ void k_shiftb(const float* __restrict__ B0, const float* __restrict__ B1,
                         const float* __restrict__ sh1, const float* __restrict__ sh2,
                         float* __restrict__ sb1, float* __restrict__ sb2){
  int c = blockIdx.x*256 + threadIdx.x;  // 0..2047
  const float* sh = blockIdx.y ? sh2 : sh1;
  float* sb = blockIdx.y ? sb2 : sb1;
  const float* B = (c < 1024) ? B0 : B1;
  int cc = c & 1023;
  float s = 0.f;
  for (int k=0;k<1024;k++) s += sh[k]*B[(size_t)k*1024 + cc];
  sb[c] = s;
}

// ---------------- MFMA GEMM (proven round-10 body): CAT = [A0|A1]@Bt^T, bf16 out ----------------
__global__ __launch_bounds__(256) void k_gemm(const u16* __restrict__ A0, const u16* __restrict__ A1,
    const u16* __restrict__ Bt, u16* __restrict__ C, int M){
  __shared__ u16 As[128*64];
  __shared__ u16 Bs[128*64];
  int lin = blockIdx.y*16 + blockIdx.x;
  int wg  = (lin&7)*470 + (lin>>3);
  int n0 = (wg & 15)*128;
  int m0 = (wg >> 4)*128;
  int t = threadIdx.x;
  int wave = t>>6, lane = t&63;
  int wm = (wave>>1)*64, wn = (wave&1)*64;
  int rr = lane&15, kq = (lane>>4)*8;
  int srow = t>>3;
  int scol = (t&7)*8;
  int ssw  = ((t&7) ^ (srow&7))*8;
  f32x4 acc[4][4];
  #pragma unroll
  for (int m=0;m<4;m++)
    #pragma unroll
    for (int n=0;n<4;n++){ acc[m][n][0]=0.f; acc[m][n][1]=0.f; acc[m][n][2]=0.f; acc[m][n][3]=0.f; }
  for (int k0=0; k0<1024; k0+=64){
    const u16* Ap = (k0 < 512) ? A0 : A1;
    int kc = k0 & 511;
    #pragma unroll
    for (int i=0;i<4;i++){
      int row = i*32 + srow;
      gload_lds16(Ap + (size_t)(m0+row)*512 + kc + ssw, As + row*64 + scol);
    }
    #pragma unroll
    for (int i=0;i<4;i++){
      int row = i*32 + srow;
      gload_lds16(Bt + (size_t)(n0+row)*1024 + k0 + ssw, Bs + row*64 + scol);
    }
    __syncthreads();
    #pragma unroll
    for (int ks=0; ks<2; ks++){
      int pc = ((ks*4 + (lane>>4)) ^ (lane&7))*8;
      bf16x8 af[4], bb[4];
      #pragma unroll
      for (int m=0;m<4;m++) af[m] = *(const bf16x8*)(&As[(wm + m*16 + rr)*64 + pc]);
      #pragma unroll
      for (int n=0;n<4;n++) bb[n] = *(const bf16x8*)(&Bs[(wn + n*16 + rr)*64 + pc]);
      #pragma unroll
      for (int m=0;m<4;m++)
        #pragma unroll
        for (int n=0;n<4;n++)
          acc[m][n] = __builtin_amdgcn_mfma_f32_16x16x32_bf16(af[m], bb[n], acc[m][n], 0, 0, 0);
    }
    __syncthreads();
  }
  int rq = (lane>>4)*4;
  #pragma unroll
  for (int m=0;m<4;m++)
    #pragma unroll
    for (int n=0;n<4;n++)
      #pragma unroll
      for (int j=0;j<4;j++){
        int row = m0 + wm + m*16 + rq + j;
        int col = n0 + wn + n*16 + rr;
        if (row < M) C[(size_t)row*2048 + col] = f2b(acc[m][n][j]);
      }
}

// ---------------- node-centric layer-2 edge pass (sb folded into rv) ----------------
__global__ __launch_bounds__(256) void k_edge2f(const int* __restrict__ ei,
    const float* __restrict__ ea,
    const int* __restrict__ rp, const int* __restrict__ eix,
    const float* __restrict__ We, const float* __restrict__ att,
    const u16* __restrict__ CAT, const float* __restrict__ sb,
    float* __restrict__ alpha){
  int lane = threadIdx.x & 63;
  int n = blockIdx.x*4 + (threadIdx.x>>6);
  if (n >= NN) return;
  int j0 = lane*16;
  float rv[16], we16[16], at16[16];
  bf16x8 rr0 = *(const bf16x8*)(CAT + (size_t)n*2048 + 1024 + j0);
  bf16x8 rr1 = *(const bf16x8*)(CAT + (size_t)n*2048 + 1024 + j0 + 8);
  #pragma unroll
  for (int j=0;j<16;j++){
    rv[j] = b2f((u16)((j<8)? rr0[j] : rr1[j-8])) + sb[1024+j0+j] + sb[j0+j];
    we16[j]=We[j0+j]; at16[j]=att[j0+j];
  }
  int e0 = rp[n], e1 = rp[n+1];
  float den = 0.f;
  for (int i=e0;i<e1;i++){
    int e = eix[i];
    int src = ei[e];
    float eaw = ea[e];
    bf16x8 l0 = *(const bf16x8*)(CAT + (size_t)src*2048 + j0);
    bf16x8 l1 = *(const bf16x8*)(CAT + (size_t)src*2048 + j0 + 8);
    float logit = 0.f;
    #pragma unroll
    for (int j=0;j<16;j++){
      float v = b2f((u16)((j<8)? l0[j] : l1[j-8])) + rv[j] + eaw*we16[j];
      v = v>0.f? v : 0.2f*v;
      logit += v*at16[j];
    }
    logit += __shfl_xor(logit,1);
    logit += __shfl_xor(logit,2);
    logit += __shfl_xor(logit,4);
    float ex_ = __expf(logit);
    if ((lane&7)==0){ alpha[(size_t)e*8 + (lane>>3)] = ex_; den += ex_; }
  }
  float dh = __shfl(den, (lane&7)*8);
  float inv = 1.f/(dh + 1e-16f);
  if (lane < 8){
    for (int i=e0;i<e1;i++){
      int e = eix[i];
      alpha[(size_t)e*8 + lane] *= inv;
    }
  }
}

// ---------------- fused layer-2 aggregation + route pooling (edge-centric) ----------------
#define ECH 32
__global__ __launch_bounds__(256) void k_agg2pool(const int* __restrict__ ei,
    const int* __restrict__ rerp, const int* __restrict__ reix,
    const int* __restrict__ rrp, const int* __restrict__ nre,
    const float* __restrict__ alpha, const u16* __restrict__ CAT,
    const float* __restrict__ b3, const float* __restrict__ sb,
    float* __restrict__ rs){
  int r = blockIdx.x;
  int c = blockIdx.z*256 + threadIdx.x;   // 0..1023
  int h = c >> 7;
  int i0 = rerp[r], i1 = rerp[r+1];
  int per = (i1 - i0 + ECH - 1)/ECH;
  int s0 = i0 + blockIdx.y*per;
  int s1 = min(i1, s0 + per);
  float acc = 0.f;
  for (int i=s0;i<s1;i++){
    int e = reix[i];
    float a = alpha[(size_t)e*8 + h];
    acc += a * b2f(CAT[(size_t)ei[e]*2048 + c]);
  }
  if (blockIdx.y == 0)
    acc += (float)(rrp[r+1]-rrp[r]) * b3[c] + (float)nre[r] * sb[c];
  if (s0 < s1 || blockIdx.y == 0) atomicAdd(&rs[r*1024 + c], acc);
}

// ---------------- fused cumsum over routes + pn BN -> H0 directly ----------------
__global__ void k_cumsum_bn(const float* __restrict__ rs1, const float* __restrict__ rs2,
                            const float* __restrict__ g, const float* __restrict__ b,
                            float* __restrict__ h){
  const float* rs = blockIdx.y ? rs2 : rs1;
  int colbase = blockIdx.y ? 2048 : 0;
  int c = blockIdx.x*256 + threadIdx.x; // 0..1023
  float tot = 0.f;
  for (int r=0;r<64;r++) tot += rs[r*1024+c];
  float cs=0.f, s0=0.f,q0=0.f,s1=0.f,q1=0.f;
  for (int r=0;r<64;r++){
    cs += rs[r*1024+c];
    float m = tot - cs;
    s0+=cs; q0+=cs*cs; s1+=m; q1+=m*m;
  }
  float mu0=s0*(1.f/64.f), v0=q0*(1.f/64.f)-mu0*mu0, n0=rsqrtf(v0+1e-5f);
  float mu1=s1*(1.f/64.f), v1=q1*(1.f/64.f)-mu1*mu1, n1=rsqrtf(v1+1e-5f);
  float g0=g[colbase+c],      b0=b[colbase+c];
  float g1=g[colbase+1024+c], b1=b[colbase+1024+c];
  cs = 0.f;
  for (int r=0;r<64;r++){
    cs += rs[r*1024+c];
    float m = tot - cs;
    h[r*4096 + colbase + c]        = (cs-mu0)*n0*g0 + b0;
    h[r*4096 + colbase + 1024 + c] = (m -mu1)*n1*g1 + b1;
  }
}

// ---------------- MLP split-K partials: PART[sk][64][Co] ----------------
#define KC 512
__global__ __launch_bounds__(256) void k_mlp_part(const float* __restrict__ In,
    const float* __restrict__ W, float* __restrict__ PART, int Ci, int Co){
  __shared__ float tin[64*64];
  int c  = blockIdx.x*64 + (threadIdx.x&63);
  int rg = threadIdx.x>>6;
  int k0 = blockIdx.y*KC, k1 = min(Ci, k0+KC);
  float acc[16];
  #pragma unroll
  for (int j=0;j<16;j++) acc[j]=0.f;
  for (int ks=k0; ks<k1; ks+=64){
    int kw = min(64, k1-ks);
    __syncthreads();
    for (int i=threadIdx.x;i<64*64;i+=256){
      int r=i>>6, k=i&63;
      tin[i] = (k<kw)? In[(size_t)r*Ci + ks + k] : 0.f;
    }
    __syncthreads();
    if (c < Co){
      for (int k=0;k<kw;k+=4){
        float4 w4;
        w4.x = W[(size_t)(ks+k  )*Co + c];
        w4.y = W[(size_t)(ks+k+1)*Co + c];
        w4.z = W[(size_t)(ks+k+2)*Co + c];
        w4.w = W[(size_t)(ks+k+3)*Co + c];
        #pragma unroll
        for (int j=0;j<16;j++){
          float4 t4 = *(const float4*)(&tin[(rg*16+j)*64 + k]);
          acc[j] += t4.x*w4.x + t4.y*w4.y + t4.z*w4.z + t4.w*w4.w;
        }
      }
    }
  }
  if (c < Co){
    float* P = PART + (size_t)blockIdx.y*64*Co;
    #pragma unroll
    for (int j=0;j<16;j++)
      P[(size_t)(rg*16+j)*Co + c] = acc[j];
  }
}

// ---------------- MLP reduce: Out = act(sum_sk PART + bias) ----------------
__global__ void k_mlp_red(const float* __restrict__ PART, const float* __restrict__ bias,
                          float* __restrict__ Out, int Co, int SK, int act){
  int idx = blockIdx.x*256 + threadIdx.x;
  if (idx >= 64*Co) return;
  int c = idx % Co;
  float s = bias[c];
  for (int sk=0; sk<SK; sk++) s += PART[(size_t)sk*64*Co + idx];
  if (act) s = s>0.f ? s : 0.01f*s;
  Out[idx] = s;
}

// ---------------- fused MLP tail: 256 -> 128 -> 64 -> 32 -> 1 + sigmoid ----------------
__global__ __launch_bounds__(256) void k_mlp_tail(const float* __restrict__ In,
    const float* __restrict__ W5, const float* __restrict__ c5,
    const float* __restrict__ W6, const float* __restrict__ c6,
    const float* __restrict__ W7, const float* __restrict__ c7,
    const float* __restrict__ W8, const float* __restrict__ c8,
    float* __restrict__ out){
  __shared__ float A[64*256];
  __shared__ float B[64*128];
  int t = threadIdx.x;
  for (int i=t;i<64*256;i+=256) A[i] = In[i];
  __syncthreads();
  // L5: 256 -> 128
  for (int idx=t; idx<64*128; idx+=256){
    int r=idx>>7, c=idx&127;
    float s=c5[c];
    for (int k=0;k<256;k++) s += A[r*256+k]*W5[k*128+c];
    B[idx] = s>0.f? s : 0.01f*s;
  }
  __syncthreads();
  // L6: 128 -> 64 (into A)
  for (int idx=t; idx<64*64; idx+=256){
    int r=idx>>6, c=idx&63;
    float s=c6[c];
    for (int k=0;k<128;k++) s += B[r*128+k]*W6[k*64+c];
    A[idx] = s>0.f? s : 0.01f*s;
  }
  __syncthreads();
  // L7: 64 -> 32 (into B)
  for (int idx=t; idx<64*32; idx+=256){
    int r=idx>>5, c=idx&31;
    float s=c7[c];
    for (int k=0;k<64;k++) s += A[r*64+k]*W7[k*32+c];
    B[idx] = s>0.f? s : 0.01f*s;
  }
  __syncthreads();
  // L8 + sigmoid
  if (t<64){
    float s=c8[0];
    for (int k=0;k<32;k++) s += B[t*32+k]*W8[k];
    out[t] = 1.f/(1.f + __expf(-s));
    out[64+t] = 0.f;
  }
}

extern "C" void kernel_launch(void* const* d_in, const int* in_sizes, int n_in,
                              void* d_out, int out_size, void* d_ws, size_t ws_size,
                              hipStream_t stream)
{
  const float* x_p1   = (const float*)d_in[0];
  const float* x_p2   = (const float*)d_in[1];
  const float* x_full = (const float*)d_in[2];
  const float* ea_p1  = (const float*)d_in[3];
  const float* ea_p2  = (const float*)d_in[4];
  const float* ea_full= (const float*)d_in[5];
  const int* ei_p1  = (const int*)d_in[6];
  const int* ei_p2  = (const int*)d_in[7];
  const int* ei_full= (const int*)d_in[8];
  const int* route_p1 = (const int*)d_in[9];
  const int* route_p2 = (const int*)d_in[10];
  const float *Wl1=(const float*)d_in[11], *Wr1=(const float*)d_in[12], *We1=(const float*)d_in[13], *att1=(const float*)d_in[14], *b1=(const float*)d_in[15];
  const float *Wl2=(const float*)d_in[16], *Wr2=(const float*)d_in[17], *We2=(const float*)d_in[18], *att2=(const float*)d_in[19], *b2=(const float*)d_in[20];
  const float *Wl3=(const float*)d_in[21], *Wr3=(const float*)d_in[22], *We3=(const float*)d_in[23], *att3=(const float*)d_in[24], *b3=(const float*)d_in[25];
  const float *bng=(const float*)d_in[26], *bnb=(const float*)d_in[27], *png=(const float*)d_in[28], *pnb=(const float*)d_in[29];
  const float *W[8], *Cb[8];
  for (int i=0;i<8;i++){ W[i]=(const float*)d_in[30+2*i]; Cb[i]=(const float*)d_in[31+2*i]; }

  char* w = (char*)d_ws;
  size_t off = 0;
  auto alloc = [&](size_t bytes)->char*{ char* p = w + off; off += (bytes + 255) & ~(size_t)255; return p; };
  u16* P1bf = (u16*)alloc((size_t)NNP*512*2);
  u16* P2bf = (u16*)alloc((size_t)NNP*512*2);
  u16* FGbf = (u16*)alloc((size_t)NNP*512*2);
  char* BIG = alloc((size_t)NN*2048*2);           // phase1: XLF|XL1|XL2  phase3: CAT
  u16*   XLF  = (u16*)BIG;
  u16*   XL1  = (u16*)(BIG + (size_t)NN*512*2);
  u16*   XL2  = (u16*)(BIG + (size_t)NN*512*2*2);
  u16*   CATbf= (u16*)BIG;
  u16*   Bt1  = (u16*)alloc((size_t)2048*1024*2);
  u16*   Bt2  = (u16*)alloc((size_t)2048*1024*2);
  float* ALPHA=(float*)alloc((size_t)EPAR*8*4);
  float* st1 = (float*)alloc(1024*4);
  float* st2 = (float*)alloc(1024*4);
  float* stF = (float*)alloc(1024*4);
  float* rs1 = (float*)alloc(64*1024*4);
  float* rs2 = (float*)alloc(64*1024*4);
  float* sc1 = (float*)alloc(1024*4);
  float* sh1 = (float*)alloc(1024*4);
  float* sc2 = (float*)alloc(1024*4);
  float* sh2 = (float*)alloc(1024*4);
  float* sb1 = (float*)alloc(2048*4);
  float* sb2 = (float*)alloc(2048*4);
  float* H0  = (float*)alloc(64*4096*4);
  float* H1  = (float*)alloc(64*4096*4);
  float* PART= (float*)alloc((size_t)8*64*2048*4);
  char* cnt_base = alloc(0);
  int* cntF = (int*)alloc(NN*4);
  int* cntA = (int*)alloc(NN*4);
  int* cntB = (int*)alloc(NN*4);
  int* c64a = (int*)alloc(64*4);
  int* c64b = (int*)alloc(64*4);
  int* c64c = (int*)alloc(64*4);
  int* c64d = (int*)alloc(64*4);
  int* nre1 = (int*)alloc(64*4);
  int* nre2 = (int*)alloc(64*4);
  size_t cnt_bytes = (size_t)((char*)alloc(0) - cnt_base);
  int* wpF = (int*)alloc(NN*4);
  int* wpA = (int*)alloc(NN*4);
  int* wpB = (int*)alloc(NN*4);
  int* w64c= (int*)alloc(64*4);
  int* w64d= (int*)alloc(64*4);
  int* rpF = (int*)alloc((NN+1)*4);
  int* rp1 = (int*)alloc((NN+1)*4);
  int* rp2 = (int*)alloc((NN+1)*4);
  int* eixF= (int*)alloc((size_t)EFULL*4);
  int* eix1= (int*)alloc((size_t)EPAR*4);
  int* eix2= (int*)alloc((size_t)EPAR*4);
  int* rr1 = (int*)alloc(65*4);
  int* rr2 = (int*)alloc(65*4);
  int* rerp1=(int*)alloc(65*4);
  int* rerp2=(int*)alloc(65*4);
  int* reix1=(int*)alloc((size_t)EPAR*4);
  int* reix2=(int*)alloc((size_t)EPAR*4);
  if (ws_size < off){ k_fail<<<1,128,0,stream>>>((float*)d_out); return; }

  // ---- zero counters (1 memset) + stats/rs (1 memset, contiguous st1..rs2) ----
  hipMemsetAsync(cnt_base, 0, cnt_bytes, stream);
  hipMemsetAsync(st1, 0, (size_t)((char*)rs2 - (char*)st1) + 64*1024*4, stream);

  // ---- batched CSR builds ----
  k_counte3<<<dim3((EFULL+255)/256,1,3), 256, 0, stream>>>(ei_full+EFULL, ei_p1+EPAR, ei_p2+EPAR,
                                                           cntF, cntA, cntB);
  k_count64<<<dim3((NN+255)/256,1,4), 256, 0, stream>>>(route_p1, route_p2, ei_p1+EPAR, ei_p2+EPAR,
                                                        c64a, c64b, c64c, c64d);
  k_scan3  <<<3, 1024, 0, stream>>>(cntF, cntA, cntB, rpF, rp1, rp2, wpF, wpA, wpB);
  k_scan64x4<<<1, 64, 0, stream>>>(c64a,c64b,c64c,c64d, rr1,rr2,rerp1,rerp2, w64c,w64d);
  k_fill_all<<<dim3((EFULL+255)/256,1,7), 256, 0, stream>>>(
      ei_full+EFULL, ei_p1+EPAR, ei_p2+EPAR, wpF, wpA, wpB, eixF, eix1, eix2,
      route_p1, route_p2, w64c, w64d, reix1, reix2, rp1, rp2, nre1, nre2);

  // ---- layer-1 GAT: batched xl, then batched fused gat ----
  k_xwl3 <<<dim3(NN,2,3), 256, 0, stream>>>(x_full, x_p1, x_p2, Wl2, Wl1, XLF, XL1, XL2);
  k_gat1f3<<<dim3((NN+3)/4,1,3), 256, 0, stream>>>(
      ei_full, ea_full, rpF, eixF, x_full, Wr2, We2, att2, XLF, b2, FGbf,
      ei_p1,   ea_p1,   rp1, eix1, x_p1,   Wr1, We1, att1, XL1, b1, P1bf,
      ei_p2,   ea_p2,   rp2, eix2, x_p2,   XL2, P2bf);

  // ---- BN stats + fold into GEMM B ----
  k_bnstats<<<dim3(120,3), 256, 0, stream>>>(P1bf, P2bf, FGbf, st1, st2, stF);
  k_prep   <<<4, 256, 0, stream>>>(st1, st2, stF, bng, bnb, sc1, sh1, sc2, sh2);
  k_bt     <<<dim3(16,16,4), 256, 0, stream>>>(Wl3, Wr3, sc1, sc2, Bt1, Bt2);
  k_shiftb <<<dim3(8,2), 256, 0, stream>>>(Wl3, Wr3, sh1, sh2, sb1, sb2);

  // ---- layer-2 GAT + fused route pooling, per parent ----
  auto layer2 = [&](const u16* Pbf, const u16* Bt, const float* sb,
                    const int* ei, const float* ea, const int* rp, const int* eix,
                    const int* rrp, const int* nre, const int* rerp, const int* reix, float* rs){
    k_gemm <<<dim3(16, (NN+127)/128), 256, 0, stream>>>(Pbf, FGbf, Bt, CATbf, NN);
    k_edge2f<<<(NN+3)/4, 256, 0, stream>>>(ei, ea, rp, eix, We3, att3, CATbf, sb, ALPHA);
    k_agg2pool<<<dim3(64,ECH,4), 256, 0, stream>>>(ei, rerp, reix, rrp, nre, ALPHA, CATbf, b3, sb, rs);
  };
  layer2(P1bf, Bt1, sb1, ei_p1, ea_p1, rp1, eix1, rr1, nre1, rerp1, reix1, rs1);
  layer2(P2bf, Bt2, sb2, ei_p2, ea_p2, rp2, eix2, rr2, nre2, rerp2, reix2, rs2);

  // ---- fused cumsum + pn BN -> H0 ----
  k_cumsum_bn<<<dim3(4,2), 256, 0, stream>>>(rs1, rs2, png, pnb, H0);

  // ---- MLP: layers 1-4 split-K, tail fused (256->128->64->32->1) ----
  int dims[5] = {4096, 2048, 1024, 512, 256};
  float* bufs[2] = {H0, H1};
  for (int i=0;i<4;i++){
    int Ci = dims[i], Co = dims[i+1];
    int SK = (Ci + KC - 1)/KC;
    k_mlp_part<<<dim3((Co+63)/64, SK), 256, 0, stream>>>(bufs[i&1], W[i], PART, Ci, Co);
    k_mlp_red <<<(64*Co+255)/256, 256, 0, stream>>>(PART, Cb[i], bufs[(i+1)&1], Co, SK, 1);
  }
  // after 4 layers result is in H0 (width 256)
  k_mlp_tail<<<1, 256, 0, stream>>>(H0, W[4], Cb[4], W[5], Cb[5], W[6], Cb[6], W[7], Cb[7],
                                    (float*)d_out);
}

// Round 14
// 1608.582 us; speedup vs baseline: 1.0970x; 1.0420x over previous
//
#include <hip/hip_runtime.h>
#include <stdint.h>

typedef unsigned short u16;
typedef unsigned int   u32;
typedef __attribute__((ext_vector_type(8))) short bf16x8;
typedef __attribute__((ext_vector_type(4))) float f32x4;

#define NN    30000
#define NNP   30208   // NN padded so unconditional 128-row GEMM tile loads stay in-bounds
#define EFULL 240000
#define EPAR  30000

__device__ __forceinline__ float b2f(u16 u){ u32 x=((u32)u)<<16; float f; __builtin_memcpy(&f,&x,4); return f; }
__device__ __forceinline__ u16 f2b(float f){ u32 x; __builtin_memcpy(&x,&f,4); x += 0x7fffu + ((x>>16)&1u); return (u16)(x>>16); }

__device__ __forceinline__ void gload_lds16(const u16* g, u16* l){
  __builtin_amdgcn_global_load_lds((const __attribute__((address_space(1))) void*)g,
                                   (__attribute__((address_space(3))) void*)l, 16, 0, 0);
}

// ---------------- sentinel: workspace too small ----------------
__global__ void k_fail(float* out){ int t=threadIdx.x; if(t<128) out[t]=2.0f; }

// ---------------- batched edge-CSR counts (z = graph: 0 full, 1 p1, 2 p2) ----------------
__global__ void k_counte3(const int* __restrict__ d0, const int* __restrict__ d1, const int* __restrict__ d2,
                          int* __restrict__ c0, int* __restrict__ c1, int* __restrict__ c2){
  int z = blockIdx.z;
  const int* d = z==0? d0 : z==1? d1 : d2;
  int* c = z==0? c0 : z==1? c1 : c2;
  int E = z==0? EFULL : EPAR;
  int e = blockIdx.x*256 + threadIdx.x;
  if (e < E) atomicAdd(&c[d[e]], 1);
}

__global__ void k_scan3(const int* __restrict__ c0, const int* __restrict__ c1, const int* __restrict__ c2,
                        int* __restrict__ r0, int* __restrict__ r1, int* __restrict__ r2,
                        int* __restrict__ w0, int* __restrict__ w1, int* __restrict__ w2){
  __shared__ int sums[1024];
  int z = blockIdx.x;
  const int* cnt = z==0? c0 : z==1? c1 : c2;
  int* rp = z==0? r0 : z==1? r1 : r2;
  int* wp = z==0? w0 : z==1? w1 : w2;
  int t = threadIdx.x;
  const int CH = (NN + 1023)/1024; // 30
  int c00 = t*CH;
  int s = 0;
  for (int i=0;i<CH;i++){ int idx=c00+i; s += (idx<NN)? cnt[idx] : 0; }
  sums[t] = s; __syncthreads();
  for (int off=1; off<1024; off<<=1){
    int v = (t>=off)? sums[t-off] : 0;
    __syncthreads();
    sums[t] += v;
    __syncthreads();
  }
  int run = (t==0)? 0 : sums[t-1];
  for (int i=0;i<CH;i++){
    int idx=c00+i;
    if (idx<NN){ rp[idx]=run; wp[idx]=run; run += cnt[idx]; }
  }
  if (t==1023) rp[NN] = sums[1023];
}

// ---------------- batched 64-bin counts (z: 0/1 route nodes, 2/3 route-of-dst edges) ----------------
__global__ void k_count64(const int* __restrict__ rt0, const int* __restrict__ rt1,
                          const int* __restrict__ d0, const int* __restrict__ d1,
                          int* __restrict__ c0, int* __restrict__ c1,
                          int* __restrict__ c2, int* __restrict__ c3){
  int z = blockIdx.z;
  int i = blockIdx.x*256 + threadIdx.x;
  if (i >= NN) return;  // NN == EPAR
  if      (z==0) atomicAdd(&c0[rt0[i]], 1);
  else if (z==1) atomicAdd(&c1[rt1[i]], 1);
  else if (z==2) atomicAdd(&c2[rt0[d0[i]]], 1);
  else           atomicAdd(&c3[rt1[d1[i]]], 1);
}

__global__ void k_scan64x4(const int* __restrict__ c0, const int* __restrict__ c1,
                           const int* __restrict__ c2, const int* __restrict__ c3,
                           int* __restrict__ r0, int* __restrict__ r1,
                           int* __restrict__ r2, int* __restrict__ r3,
                           int* __restrict__ w2, int* __restrict__ w3){
  int t = threadIdx.x;
  if (t >= 4) return;
  const int* c = t==0?c0:t==1?c1:t==2?c2:c3;
  int* r = t==0?r0:t==1?r1:t==2?r2:r3;
  int run=0;
  for (int i=0;i<64;i++){
    r[i]=run;
    if (t==2) w2[i]=run;
    if (t==3) w3[i]=run;
    run+=c[i];
  }
  r[64]=run;
}

// ---------------- merged fills: z=0..2 edge CSR, z=3..4 route-edge CSR, z=5..6 nre ----------------
__global__ void k_fill_all(
    const int* __restrict__ dF, const int* __restrict__ d1, const int* __restrict__ d2,
    int* __restrict__ wF, int* __restrict__ wA, int* __restrict__ wB,
    int* __restrict__ xF, int* __restrict__ x1, int* __restrict__ x2,
    const int* __restrict__ rt1, const int* __restrict__ rt2,
    int* __restrict__ w64c, int* __restrict__ w64d,
    int* __restrict__ reix1, int* __restrict__ reix2,
    const int* __restrict__ rp1, const int* __restrict__ rp2,
    int* __restrict__ nre1, int* __restrict__ nre2){
  int z = blockIdx.z;
  int i = blockIdx.x*256 + threadIdx.x;
  if      (z==0){ if (i<EFULL){ int p=atomicAdd(&wF[dF[i]],1);          xF[p]=i; } }
  else if (z==1){ if (i<EPAR) { int p=atomicAdd(&wA[d1[i]],1);          x1[p]=i; } }
  else if (z==2){ if (i<EPAR) { int p=atomicAdd(&wB[d2[i]],1);          x2[p]=i; } }
  else if (z==3){ if (i<EPAR) { int p=atomicAdd(&w64c[rt1[d1[i]]],1);   reix1[p]=i; } }
  else if (z==4){ if (i<EPAR) { int p=atomicAdd(&w64d[rt2[d2[i]]],1);   reix2[p]=i; } }
  else if (z==5){ if (i<NN && rp1[i+1]>rp1[i]) atomicAdd(&nre1[rt1[i]],1); }
  else          { if (i<NN && rp2[i+1]>rp2[i]) atomicAdd(&nre2[rt2[i]],1); }
}

// ---------------- layer-1 xl = x@Wl, batched over 3 graphs (z) ----------------
__global__ __launch_bounds__(256) void k_xwl3(const float* __restrict__ xf,
    const float* __restrict__ x1, const float* __restrict__ x2,
    const float* __restrict__ WlF, const float* __restrict__ WlP,
    u16* __restrict__ xlF, u16* __restrict__ xl1, u16* __restrict__ xl2){
  int z = blockIdx.z;
  const float* x = z==0? xf : z==1? x1 : x2;
  const float* Wl = z==0? WlF : WlP;
  u16* xl = z==0? xlF : z==1? xl1 : xl2;
  int n = blockIdx.x;
  int c = blockIdx.y*256 + threadIdx.x;
  float a=0.f;
  #pragma unroll
  for (int k=0;k<16;k++) a += x[n*16+k]*Wl[k*512+c];
  xl[(size_t)n*512+c]=f2b(a);
}

// ---------------- fused layer-1 GAT, batched over 3 graphs (z), pipelined gathers ----------------
__global__ __launch_bounds__(256) void k_gat1f3(
    const int* __restrict__ eiF, const float* __restrict__ eaF,
    const int* __restrict__ rpF, const int* __restrict__ eixF,
    const float* __restrict__ xF, const float* __restrict__ WrF,
    const float* __restrict__ WeF, const float* __restrict__ attF,
    const u16* __restrict__ xlF, const float* __restrict__ bF, u16* __restrict__ outF,
    const int* __restrict__ ei1, const float* __restrict__ ea1,
    const int* __restrict__ rp1, const int* __restrict__ eix1,
    const float* __restrict__ x1p, const float* __restrict__ WrP,
    const float* __restrict__ WeP, const float* __restrict__ attP,
    const u16* __restrict__ xl1, const float* __restrict__ bP, u16* __restrict__ out1,
    const int* __restrict__ ei2, const float* __restrict__ ea2,
    const int* __restrict__ rp2, const int* __restrict__ eix2,
    const float* __restrict__ x2p, const u16* __restrict__ xl2, u16* __restrict__ out2){
  int z = blockIdx.z;
  const int* ei  = z==0? eiF : z==1? ei1 : ei2;
  const float* ea= z==0? eaF : z==1? ea1 : ea2;
  const int* rp  = z==0? rpF : z==1? rp1 : rp2;
  const int* eix = z==0? eixF: z==1? eix1: eix2;
  const float* x = z==0? xF  : z==1? x1p : x2p;
  const float* Wr= z==0? WrF : WrP;
  const float* We= z==0? WeF : WeP;
  const float* att=z==0? attF: attP;
  const u16* xl  = z==0? xlF : z==1? xl1 : xl2;
  const float* bias = z==0? bF : bP;
  u16* out = z==0? outF : z==1? out1 : out2;

  int lane = threadIdx.x & 63;
  int n = blockIdx.x*4 + (threadIdx.x>>6);
  if (n >= NN) return;
  int j0 = lane*8;
  float xv[16];
  #pragma unroll
  for (int k=0;k<16;k++) xv[k] = x[n*16+k];
  float we8[8], at8[8], rv8[8];
  #pragma unroll
  for (int j=0;j<8;j++){
    we8[j]=We[j0+j]; at8[j]=att[j0+j];
    float s=0.f;
    #pragma unroll
    for (int k=0;k<16;k++) s += xv[k]*Wr[k*512 + j0 + j];
    rv8[j]=s;
  }
  int r0 = rp[n], r1 = rp[n+1];
  float den = 0.f;
  float acc[8] = {0,0,0,0,0,0,0,0};
  for (int base=r0; base<r1; base+=64){
    int cnt = min(64, r1-base);
    // cooperative index gather: one dependent chain for the whole chunk
    int mysrc=0; float myea=0.f;
    if (lane < cnt){ int e = eix[base+lane]; mysrc = ei[e]; myea = ea[e]; }
    int scur = __shfl(mysrc, 0);
    float eacur = __shfl(myea, 0);
    bf16x8 rowc = *(const bf16x8*)(xl + (size_t)scur*512 + j0);
    for (int i=0;i<cnt;i++){
      bf16x8 rown = rowc; float ean = 0.f;
      if (i+1 < cnt){
        int sn = __shfl(mysrc, i+1);
        ean = __shfl(myea, i+1);
        rown = *(const bf16x8*)(xl + (size_t)sn*512 + j0);   // prefetch next row
      }
      float lvf[8];
      float logit = 0.f;
      #pragma unroll
      for (int j=0;j<8;j++){
        lvf[j] = b2f((u16)rowc[j]);
        float v = lvf[j] + rv8[j] + eacur*we8[j];
        v = v>0.f? v : 0.2f*v;
        logit += v*at8[j];
      }
      logit += __shfl_xor(logit,1);
      logit += __shfl_xor(logit,2);
      logit += __shfl_xor(logit,4);
      float a = __expf(logit);
      den += a;
      #pragma unroll
      for (int j=0;j<8;j++) acc[j] += a*lvf[j];
      rowc = rown; eacur = ean;
    }
  }
  float inv = 1.f/(den + 1e-16f);
  #pragma unroll
  for (int j=0;j<8;j++) out[(size_t)n*512 + j0 + j] = f2b(acc[j]*inv + bias[j0+j]);
}

// ---------------- BN stats, batched z=3, coalesced row-band ----------------
__global__ __launch_bounds__(256) void k_bnstats(const u16* __restrict__ P1, const u16* __restrict__ P2,
    const u16* __restrict__ PF, float* __restrict__ s1, float* __restrict__ s2, float* __restrict__ sF){
  int z = blockIdx.y;
  const u16* P = z==0? P1 : z==1? P2 : PF;
  float* st = z==0? s1 : z==1? s2 : sF;
  int t = threadIdx.x;
  const u32* Pu = (const u32*)P;
  int r0 = blockIdx.x*250, r1 = r0+250;
  float a0=0.f,a1=0.f,q0=0.f,q1=0.f;
  for (int r=r0;r<r1;r++){
    u32 v = Pu[(size_t)r*256 + t];
    float a = b2f((u16)(v & 0xffffu));
    float b = b2f((u16)(v >> 16));
    a0+=a; q0+=a*a; a1+=b; q1+=b*b;
  }
  atomicAdd(&st[2*t],       a0);
  atomicAdd(&st[2*t+1],     a1);
  atomicAdd(&st[512+2*t],   q0);
  atomicAdd(&st[512+2*t+1], q1);
}

// ---------------- BN fold prep: per-parent scale/shift over A's 1024 k-columns ----------------
__global__ void k_prep(const float* __restrict__ st1, const float* __restrict__ st2,
                       const float* __restrict__ stF,
                       const float* __restrict__ g, const float* __restrict__ b,
                       float* __restrict__ sc1, float* __restrict__ sh1,
                       float* __restrict__ sc2, float* __restrict__ sh2){
  int k = blockIdx.x*256 + threadIdx.x;
  if (k >= 1024) return;
  const float invN = 1.f/30000.f;
  const float* st = (k<512)? st1 : stF;
  int kk = k & 511;
  float mu = st[kk]*invN;
  float var = st[512+kk]*invN - mu*mu;
  float sc = g[k]*rsqrtf(var + 1e-5f);
  sc1[k] = sc; sh1[k] = b[k] - mu*sc;
  st = (k<512)? st2 : stF;
  mu = st[kk]*invN;
  var = st[512+kk]*invN - mu*mu;
  sc = g[k]*rsqrtf(var + 1e-5f);
  sc2[k] = sc; sh2[k] = b[k] - mu*sc;
}

// ---------------- B pre-transpose + scale + bf16: Bt_p[2048][1024] ----------------
__global__ __launch_bounds__(256) void k_bt(const float* __restrict__ B0, const float* __restrict__ B1,
                                            const float* __restrict__ sc1, const float* __restrict__ sc2,
                                            u16* __restrict__ Bt1, u16* __restrict__ Bt2){
  __shared__ float tile[64][65];
  int bk = blockIdx.x;
  int bn = blockIdx.y;
  int par = blockIdx.z>>1, half = blockIdx.z&1;
  const float* B = half ? B1 : B0;
  const float* sc = par ? sc2 : sc1;
  u16* Bt = par ? Bt2 : Bt1;
  int nb = half*1024;
  for (int i = threadIdx.x; i < 64*64; i += 256){
    int r = i>>6, c = i&63;
    tile[c][r] = B[(size_t)(bk*64+r)*1024 + bn*64 + c] * sc[bk*64+r];
  }
  __syncthreads();
  for (int i = threadIdx.x; i < 64*64; i += 256){
    int r = i>>6, c = i&63;
    Bt[(size_t)(nb + bn*64 + r)*1024 + bk*64 + c] = f2b(tile[r][c]);
  }
}

// ---------------- shiftB[n] = sum_k shift[k]*B[k][n], per parent ----------------
__global__ void k_shiftb(const float* __restrict__ B0, const float* __restrict__ B1,
                         const float* __restrict__ sh1, const float* __restrict__ sh2,
                         float* __restrict__ sb1, float* __restrict__ sb2){
  int c = blockIdx.x*256 + threadIdx.x;  // 0..2047
  const float* sh = blockIdx.y ? sh2 : sh1;
  float* sb = blockIdx.y ? sb2 : sb1;
  const float* B = (c < 1024) ? B0 : B1;
  int cc = c & 1023;
  float s = 0.f;
  for (int k=0;k<1024;k++) s += sh[k]*B[(size_t)k*1024 + cc];
  sb[c] = s;
}

// ---------------- MFMA GEMM (proven round-10 body): CAT = [A0|A1]@Bt^T, bf16 out ----------------
__global__ __launch_bounds__(256) void k_gemm(const u16* __restrict__ A0, const u16* __restrict__ A1,
    const u16* __restrict__ Bt, u16* __restrict__ C, int M){
  __shared__ u16 As[128*64];
  __shared__ u16 Bs[128*64];
  int lin = blockIdx.y*16 + blockIdx.x;
  int wg  = (lin&7)*470 + (lin>>3);
  int n0 = (wg & 15)*128;
  int m0 = (wg >> 4)*128;
  int t = threadIdx.x;
  int wave = t>>6, lane = t&63;
  int wm = (wave>>1)*64, wn = (wave&1)*64;
  int rr = lane&15, kq = (lane>>4)*8;
  int srow = t>>3;
  int scol = (t&7)*8;
  int ssw  = ((t&7) ^ (srow&7))*8;
  f32x4 acc[4][4];
  #pragma unroll
  for (int m=0;m<4;m++)
    #pragma unroll
    for (int n=0;n<4;n++){ acc[m][n][0]=0.f; acc[m][n][1]=0.f; acc[m][n][2]=0.f; acc[m][n][3]=0.f; }
  for (int k0=0; k0<1024; k0+=64){
    const u16* Ap = (k0 < 512) ? A0 : A1;
    int kc = k0 & 511;
    #pragma unroll
    for (int i=0;i<4;i++){
      int row = i*32 + srow;
      gload_lds16(Ap + (size_t)(m0+row)*512 + kc + ssw, As + row*64 + scol);
    }
    #pragma unroll
    for (int i=0;i<4;i++){
      int row = i*32 + srow;
      gload_lds16(Bt + (size_t)(n0+row)*1024 + k0 + ssw, Bs + row*64 + scol);
    }
    __syncthreads();
    #pragma unroll
    for (int ks=0; ks<2; ks++){
      int pc = ((ks*4 + (lane>>4)) ^ (lane&7))*8;
      bf16x8 af[4], bb[4];
      #pragma unroll
      for (int m=0;m<4;m++) af[m] = *(const bf16x8*)(&As[(wm + m*16 + rr)*64 + pc]);
      #pragma unroll
      for (int n=0;n<4;n++) bb[n] = *(const bf16x8*)(&Bs[(wn + n*16 + rr)*64 + pc]);
      #pragma unroll
      for (int m=0;m<4;m++)
        #pragma unroll
        for (int n=0;n<4;n++)
          acc[m][n] = __builtin_amdgcn_mfma_f32_16x16x32_bf16(af[m], bb[n], acc[m][n], 0, 0, 0);
    }
    __syncthreads();
  }
  int rq = (lane>>4)*4;
  #pragma unroll
  for (int m=0;m<4;m++)
    #pragma unroll
    for (int n=0;n<4;n++)
      #pragma unroll
      for (int j=0;j<4;j++){
        int row = m0 + wm + m*16 + rq + j;
        int col = n0 + wn + n*16 + rr;
        if (row < M) C[(size_t)row*2048 + col] = f2b(acc[m][n][j]);
      }
}

// ---------------- node-centric layer-2 edge pass (sb folded into rv), pipelined gathers ----------------
__global__ __launch_bounds__(256) void k_edge2f(const int* __restrict__ ei,
    const float* __restrict__ ea,
    const int* __restrict__ rp, const int* __restrict__ eix,
    const float* __restrict__ We, const float* __restrict__ att,
    const u16* __restrict__ CAT, const float* __restrict__ sb,
    float* __restrict__ alpha){
  int lane = threadIdx.x & 63;
  int n = blockIdx.x*4 + (threadIdx.x>>6);
  if (n >= NN) return;
  int j0 = lane*16;
  float rv[16], we16[16], at16[16];
  bf16x8 rr0 = *(const bf16x8*)(CAT + (size_t)n*2048 + 1024 + j0);
  bf16x8 rr1 = *(const bf16x8*)(CAT + (size_t)n*2048 + 1024 + j0 + 8);
  #pragma unroll
  for (int j=0;j<16;j++){
    rv[j] = b2f((u16)((j<8)? rr0[j] : rr1[j-8])) + sb[1024+j0+j] + sb[j0+j];
    we16[j]=We[j0+j]; at16[j]=att[j0+j];
  }
  int e0 = rp[n], e1 = rp[n+1];
  float den = 0.f;
  for (int base=e0; base<e1; base+=64){
    int cnt = min(64, e1-base);
    int myE=0, mysrc=0; float myea=0.f;
    if (lane < cnt){ myE = eix[base+lane]; mysrc = ei[myE]; myea = ea[myE]; }
    int scur = __shfl(mysrc, 0);
    float eacur = __shfl(myea, 0);
    bf16x8 l0c = *(const bf16x8*)(CAT + (size_t)scur*2048 + j0);
    bf16x8 l1c = *(const bf16x8*)(CAT + (size_t)scur*2048 + j0 + 8);
    for (int i=0;i<cnt;i++){
      int ecur = __shfl(myE, i);
      bf16x8 l0n = l0c, l1n = l1c; float ean = 0.f;
      if (i+1 < cnt){
        int sn = __shfl(mysrc, i+1);
        ean = __shfl(myea, i+1);
        l0n = *(const bf16x8*)(CAT + (size_t)sn*2048 + j0);
        l1n = *(const bf16x8*)(CAT + (size_t)sn*2048 + j0 + 8);
      }
      float logit = 0.f;
      #pragma unroll
      for (int j=0;j<16;j++){
        float v = b2f((u16)((j<8)? l0c[j] : l1c[j-8])) + rv[j] + eacur*we16[j];
        v = v>0.f? v : 0.2f*v;
        logit += v*at16[j];
      }
      logit += __shfl_xor(logit,1);
      logit += __shfl_xor(logit,2);
      logit += __shfl_xor(logit,4);
      float ex_ = __expf(logit);
      den += ex_;                                  // same value across each 8-lane subgroup
      if ((lane&7)==0) alpha[(size_t)ecur*8 + (lane>>3)] = ex_;
      l0c = l0n; l1c = l1n; eacur = ean;
    }
  }
  float dh = __shfl(den, (lane&7)*8);   // lane l gets den of head (l&7)
  float inv = 1.f/(dh + 1e-16f);
  // normalize: 8 edges per step, all 64 lanes active (edge = lane>>3, head = lane&7)
  for (int base=e0; base<e1; base+=8){
    int idx = base + (lane>>3);
    if (idx < e1){
      int e = eix[idx];
      alpha[(size_t)e*8 + (lane&7)] *= inv;
    }
  }
}

// ---------------- fused layer-2 aggregation + route pooling (edge-centric) ----------------
#define ECH 32
__global__ __launch_bounds__(256) void k_agg2pool(const int* __restrict__ ei,
    const int* __restrict__ rerp, const int* __restrict__ reix,
    const int* __restrict__ rrp, const int* __restrict__ nre,
    const float* __restrict__ alpha, const u16* __restrict__ CAT,
    const float* __restrict__ b3, const float* __restrict__ sb,
    float* __restrict__ rs){
  int r = blockIdx.x;
  int c = blockIdx.z*256 + threadIdx.x;   // 0..1023
  int h = c >> 7;
  int i0 = rerp[r], i1 = rerp[r+1];
  int per = (i1 - i0 + ECH - 1)/ECH;
  int s0 = i0 + blockIdx.y*per;
  int s1 = min(i1, s0 + per);
  float acc = 0.f;
  for (int i=s0;i<s1;i++){
    int e = reix[i];
    float a = alpha[(size_t)e*8 + h];
    acc += a * b2f(CAT[(size_t)ei[e]*2048 + c]);
  }
  if (blockIdx.y == 0)
    acc += (float)(rrp[r+1]-rrp[r]) * b3[c] + (float)nre[r] * sb[c];
  if (s0 < s1 || blockIdx.y == 0) atomicAdd(&rs[r*1024 + c], acc);
}

// ---------------- fused cumsum over routes + pn BN -> H0 directly ----------------
__global__ void k_cumsum_bn(const float* __restrict__ rs1, const float* __restrict__ rs2,
                            const float* __restrict__ g, const float* __restrict__ b,
                            float* __restrict__ h){
  const float* rs = blockIdx.y ? rs2 : rs1;
  int colbase = blockIdx.y ? 2048 : 0;
  int c = blockIdx.x*256 + threadIdx.x; // 0..1023
  float tot = 0.f;
  for (int r=0;r<64;r++) tot += rs[r*1024+c];
  float cs=0.f, s0=0.f,q0=0.f,s1=0.f,q1=0.f;
  for (int r=0;r<64;r++){
    cs += rs[r*1024+c];
    float m = tot - cs;
    s0+=cs; q0+=cs*cs; s1+=m; q1+=m*m;
  }
  float mu0=s0*(1.f/64.f), v0=q0*(1.f/64.f)-mu0*mu0, n0=rsqrtf(v0+1e-5f);
  float mu1=s1*(1.f/64.f), v1=q1*(1.f/64.f)-mu1*mu1, n1=rsqrtf(v1+1e-5f);
  float g0=g[colbase+c],      b0=b[colbase+c];
  float g1=g[colbase+1024+c], b1=b[colbase+1024+c];
  cs = 0.f;
  for (int r=0;r<64;r++){
    cs += rs[r*1024+c];
    float m = tot - cs;
    h[r*4096 + colbase + c]        = (cs-mu0)*n0*g0 + b0;
    h[r*4096 + colbase + 1024 + c] = (m -mu1)*n1*g1 + b1;
  }
}

// ---------------- MLP split-K partials: PART[sk][64][Co] ----------------
#define KC 512
__global__ __launch_bounds__(256) void k_mlp_part(const float* __restrict__ In,
    const float* __restrict__ W, float* __restrict__ PART, int Ci, int Co){
  __shared__ float tin[64*64];
  int c  = blockIdx.x*64 + (threadIdx.x&63);
  int rg = threadIdx.x>>6;
  int k0 = blockIdx.y*KC, k1 = min(Ci, k0+KC);
  float acc[16];
  #pragma unroll
  for (int j=0;j<16;j++) acc[j]=0.f;
  for (int ks=k0; ks<k1; ks+=64){
    int kw = min(64, k1-ks);
    __syncthreads();
    for (int i=threadIdx.x;i<64*64;i+=256){
      int r=i>>6, k=i&63;
      tin[i] = (k<kw)? In[(size_t)r*Ci + ks + k] : 0.f;
    }
    __syncthreads();
    if (c < Co){
      for (int k=0;k<kw;k+=4){
        float4 w4;
        w4.x = W[(size_t)(ks+k  )*Co + c];
        w4.y = W[(size_t)(ks+k+1)*Co + c];
        w4.z = W[(size_t)(ks+k+2)*Co + c];
        w4.w = W[(size_t)(ks+k+3)*Co + c];
        #pragma unroll
        for (int j=0;j<16;j++){
          float4 t4 = *(const float4*)(&tin[(rg*16+j)*64 + k]);
          acc[j] += t4.x*w4.x + t4.y*w4.y + t4.z*w4.z + t4.w*w4.w;
        }
      }
    }
  }
  if (c < Co){
    float* P = PART + (size_t)blockIdx.y*64*Co;
    #pragma unroll
    for (int j=0;j<16;j++)
      P[(size_t)(rg*16+j)*Co + c] = acc[j];
  }
}

// ---------------- MLP reduce: Out = act(sum_sk PART + bias) ----------------
__global__ void k_mlp_red(const float* __restrict__ PART, const float* __restrict__ bias,
                          float* __restrict__ Out, int Co, int SK, int act){
  int idx = blockIdx.x*256 + threadIdx.x;
  if (idx >= 64*Co) return;
  int c = idx % Co;
  float s = bias[c];
  for (int sk=0; sk<SK; sk++) s += PART[(size_t)sk*64*Co + idx];
  if (act) s = s>0.f ? s : 0.01f*s;
  Out[idx] = s;
}

// ---------------- fused MLP tail: 256 -> 128 -> 64 -> 32 -> 1 + sigmoid ----------------
__global__ __launch_bounds__(256) void k_mlp_tail(const float* __restrict__ In,
    const float* __restrict__ W5, const float* __restrict__ c5,
    const float* __restrict__ W6, const float* __restrict__ c6,
    const float* __restrict__ W7, const float* __restrict__ c7,
    const float* __restrict__ W8, const float* __restrict__ c8,
    float* __restrict__ out){
  __shared__ float A[64*256];
  __shared__ float B[64*128];
  int t = threadIdx.x;
  for (int i=t;i<64*256;i+=256) A[i] = In[i];
  __syncthreads();
  // L5: 256 -> 128
  for (int idx=t; idx<64*128; idx+=256){
    int r=idx>>7, c=idx&127;
    float s=c5[c];
    for (int k=0;k<256;k++) s += A[r*256+k]*W5[k*128+c];
    B[idx] = s>0.f? s : 0.01f*s;
  }
  __syncthreads();
  // L6: 128 -> 64 (into A)
  for (int idx=t; idx<64*64; idx+=256){
    int r=idx>>6, c=idx&63;
    float s=c6[c];
    for (int k=0;k<128;k++) s += B[r*128+k]*W6[k*64+c];
    A[idx] = s>0.f? s : 0.01f*s;
  }
  __syncthreads();
  // L7: 64 -> 32 (into B)
  for (int idx=t; idx<64*32; idx+=256){
    int r=idx>>5, c=idx&31;
    float s=c7[c];
    for (int k=0;k<64;k++) s += A[r*64+k]*W7[k*32+c];
    B[idx] = s>0.f? s : 0.01f*s;
  }
  __syncthreads();
  // L8 + sigmoid
  if (t<64){
    float s=c8[0];
    for (int k=0;k<32;k++) s += B[t*32+k]*W8[k];
    out[t] = 1.f/(1.f + __expf(-s));
    out[64+t] = 0.f;
  }
}

extern "C" void kernel_launch(void* const* d_in, const int* in_sizes, int n_in,
                              void* d_out, int out_size, void* d_ws, size_t ws_size,
                              hipStream_t stream)
{
  const float* x_p1   = (const float*)d_in[0];
  const float* x_p2   = (const float*)d_in[1];
  const float* x_full = (const float*)d_in[2];
  const float* ea_p1  = (const float*)d_in[3];
  const float* ea_p2  = (const float*)d_in[4];
  const float* ea_full= (const float*)d_in[5];
  const int* ei_p1  = (const int*)d_in[6];
  const int* ei_p2  = (const int*)d_in[7];
  const int* ei_full= (const int*)d_in[8];
  const int* route_p1 = (const int*)d_in[9];
  const int* route_p2 = (const int*)d_in[10];
  const float *Wl1=(const float*)d_in[11], *Wr1=(const float*)d_in[12], *We1=(const float*)d_in[13], *att1=(const float*)d_in[14], *b1=(const float*)d_in[15];
  const float *Wl2=(const float*)d_in[16], *Wr2=(const float*)d_in[17], *We2=(const float*)d_in[18], *att2=(const float*)d_in[19], *b2=(const float*)d_in[20];
  const float *Wl3=(const float*)d_in[21], *Wr3=(const float*)d_in[22], *We3=(const float*)d_in[23], *att3=(const float*)d_in[24], *b3=(const float*)d_in[25];
  const float *bng=(const float*)d_in[26], *bnb=(const float*)d_in[27], *png=(const float*)d_in[28], *pnb=(const float*)d_in[29];
  const float *W[8], *Cb[8];
  for (int i=0;i<8;i++){ W[i]=(const float*)d_in[30+2*i]; Cb[i]=(const float*)d_in[31+2*i]; }

  char* w = (char*)d_ws;
  size_t off = 0;
  auto alloc = [&](size_t bytes)->char*{ char* p = w + off; off += (bytes + 255) & ~(size_t)255; return p; };
  u16* P1bf = (u16*)alloc((size_t)NNP*512*2);
  u16* P2bf = (u16*)alloc((size_t)NNP*512*2);
  u16* FGbf = (u16*)alloc((size_t)NNP*512*2);
  char* BIG = alloc((size_t)NN*2048*2);           // phase1: XLF|XL1|XL2  phase3: CAT
  u16*   XLF  = (u16*)BIG;
  u16*   XL1  = (u16*)(BIG + (size_t)NN*512*2);
  u16*   XL2  = (u16*)(BIG + (size_t)NN*512*2*2);
  u16*   CATbf= (u16*)BIG;
  u16*   Bt1  = (u16*)alloc((size_t)2048*1024*2);
  u16*   Bt2  = (u16*)alloc((size_t)2048*1024*2);
  float* ALPHA=(float*)alloc((size_t)EPAR*8*4);
  float* st1 = (float*)alloc(1024*4);
  float* st2 = (float*)alloc(1024*4);
  float* stF = (float*)alloc(1024*4);
  float* rs1 = (float*)alloc(64*1024*4);
  float* rs2 = (float*)alloc(64*1024*4);
  float* sc1 = (float*)alloc(1024*4);
  float* sh1 = (float*)alloc(1024*4);
  float* sc2 = (float*)alloc(1024*4);
  float* sh2 = (float*)alloc(1024*4);
  float* sb1 = (float*)alloc(2048*4);
  float* sb2 = (float*)alloc(2048*4);
  float* H0  = (float*)alloc(64*4096*4);
  float* H1  = (float*)alloc(64*4096*4);
  float* PART= (float*)alloc((size_t)8*64*2048*4);
  char* cnt_base = alloc(0);
  int* cntF = (int*)alloc(NN*4);
  int* cntA = (int*)alloc(NN*4);
  int* cntB = (int*)alloc(NN*4);
  int* c64a = (int*)alloc(64*4);
  int* c64b = (int*)alloc(64*4);
  int* c64c = (int*)alloc(64*4);
  int* c64d = (int*)alloc(64*4);
  int* nre1 = (int*)alloc(64*4);
  int* nre2 = (int*)alloc(64*4);
  size_t cnt_bytes = (size_t)((char*)alloc(0) - cnt_base);
  int* wpF = (int*)alloc(NN*4);
  int* wpA = (int*)alloc(NN*4);
  int* wpB = (int*)alloc(NN*4);
  int* w64c= (int*)alloc(64*4);
  int* w64d= (int*)alloc(64*4);
  int* rpF = (int*)alloc((NN+1)*4);
  int* rp1 = (int*)alloc((NN+1)*4);
  int* rp2 = (int*)alloc((NN+1)*4);
  int* eixF= (int*)alloc((size_t)EFULL*4);
  int* eix1= (int*)alloc((size_t)EPAR*4);
  int* eix2= (int*)alloc((size_t)EPAR*4);
  int* rr1 = (int*)alloc(65*4);
  int* rr2 = (int*)alloc(65*4);
  int* rerp1=(int*)alloc(65*4);
  int* rerp2=(int*)alloc(65*4);
  int* reix1=(int*)alloc((size_t)EPAR*4);
  int* reix2=(int*)alloc((size_t)EPAR*4);
  if (ws_size < off){ k_fail<<<1,128,0,stream>>>((float*)d_out); return; }

  // ---- zero counters (1 memset) + stats/rs (1 memset, contiguous st1..rs2) ----
  hipMemsetAsync(cnt_base, 0, cnt_bytes, stream);
  hipMemsetAsync(st1, 0, (size_t)((char*)rs2 - (char*)st1) + 64*1024*4, stream);

  // ---- batched CSR builds ----
  k_counte3<<<dim3((EFULL+255)/256,1,3), 256, 0, stream>>>(ei_full+EFULL, ei_p1+EPAR, ei_p2+EPAR,
                                                           cntF, cntA, cntB);
  k_count64<<<dim3((NN+255)/256,1,4), 256, 0, stream>>>(route_p1, route_p2, ei_p1+EPAR, ei_p2+EPAR,
                                                        c64a, c64b, c64c, c64d);
  k_scan3  <<<3, 1024, 0, stream>>>(cntF, cntA, cntB, rpF, rp1, rp2, wpF, wpA, wpB);
  k_scan64x4<<<1, 64, 0, stream>>>(c64a,c64b,c64c,c64d, rr1,rr2,rerp1,rerp2, w64c,w64d);
  k_fill_all<<<dim3((EFULL+255)/256,1,7), 256, 0, stream>>>(
      ei_full+EFULL, ei_p1+EPAR, ei_p2+EPAR, wpF, wpA, wpB, eixF, eix1, eix2,
      route_p1, route_p2, w64c, w64d, reix1, reix2, rp1, rp2, nre1, nre2);

  // ---- layer-1 GAT: batched xl, then batched fused gat ----
  k_xwl3 <<<dim3(NN,2,3), 256, 0, stream>>>(x_full, x_p1, x_p2, Wl2, Wl1, XLF, XL1, XL2);
  k_gat1f3<<<dim3((NN+3)/4,1,3), 256, 0, stream>>>(
      ei_full, ea_full, rpF, eixF, x_full, Wr2, We2, att2, XLF, b2, FGbf,
      ei_p1,   ea_p1,   rp1, eix1, x_p1,   Wr1, We1, att1, XL1, b1, P1bf,
      ei_p2,   ea_p2,   rp2, eix2, x_p2,   XL2, P2bf);

  // ---- BN stats + fold into GEMM B ----
  k_bnstats<<<dim3(120,3), 256, 0, stream>>>(P1bf, P2bf, FGbf, st1, st2, stF);
  k_prep   <<<4, 256, 0, stream>>>(st1, st2, stF, bng, bnb, sc1, sh1, sc2, sh2);
  k_bt     <<<dim3(16,16,4), 256, 0, stream>>>(Wl3, Wr3, sc1, sc2, Bt1, Bt2);
  k_shiftb <<<dim3(8,2), 256, 0, stream>>>(Wl3, Wr3, sh1, sh2, sb1, sb2);

  // ---- layer-2 GAT + fused route pooling, per parent ----
  auto layer2 = [&](const u16* Pbf, const u16* Bt, const float* sb,
                    const int* ei, const float* ea, const int* rp, const int* eix,
                    const int* rrp, const int* nre, const int* rerp, const int* reix, float* rs){
    k_gemm <<<dim3(16, (NN+127)/128), 256, 0, stream>>>(Pbf, FGbf, Bt, CATbf, NN);
    k_edge2f<<<(NN+3)/4, 256, 0, stream>>>(ei, ea, rp, eix, We3, att3, CATbf, sb, ALPHA);
    k_agg2pool<<<dim3(64,ECH,4), 256, 0, stream>>>(ei, rerp, reix, rrp, nre, ALPHA, CATbf, b3, sb, rs);
  };
  layer2(P1bf, Bt1, sb1, ei_p1, ea_p1, rp1, eix1, rr1, nre1, rerp1, reix1, rs1);
  layer2(P2bf, Bt2, sb2, ei_p2, ea_p2, rp2, eix2, rr2, nre2, rerp2, reix2, rs2);

  // ---- fused cumsum + pn BN -> H0 ----
  k_cumsum_bn<<<dim3(4,2), 256, 0, stream>>>(rs1, rs2, png, pnb, H0);

  // ---- MLP: layers 1-4 split-K, tail fused (256->128->64->32->1) ----
  int dims[5] = {4096, 2048, 1024, 512, 256};
  float* bufs[2] = {H0, H1};
  for (int i=0;i<4;i++){
    int Ci = dims[i], Co = dims[i+1];
    int SK = (Ci + KC - 1)/KC;
    k_mlp_part<<<dim3((Co+63)/64, SK), 256, 0, stream>>>(bufs[i&1], W[i], PART, Ci, Co);
    k_mlp_red <<<(64*Co+255)/256, 256, 0, stream>>>(PART, Cb[i], bufs[(i+1)&1], Co, SK, 1);
  }
  // after 4 layers result is in H0 (width 256)
  k_mlp_tail<<<1, 256, 0, stream>>>(H0, W[4], Cb[4], W[5], Cb[5], W[6], Cb[6], W[7], Cb[7],
                                    (float*)d_out);
}

// Round 15
// 1546.612 us; speedup vs baseline: 1.1409x; 1.0401x over previous
//
#include <hip/hip_runtime.h>
#include <stdint.h>

typedef unsigned short u16;
typedef unsigned int   u32;
typedef __attribute__((ext_vector_type(8))) short bf16x8;
typedef __attribute__((ext_vector_type(4))) float f32x4;

#define NN    30000
#define NNP   30208
#define EFULL 240000
#define EPAR  30000

__device__ __forceinline__ float b2f(u16 u){ u32 x=((u32)u)<<16; float f; __builtin_memcpy(&f,&x,4); return f; }
__device__ __forceinline__ u16 f2b(float f){ u32 x; __builtin_memcpy(&x,&f,4); x += 0x7fffu + ((x>>16)&1u); return (u16)(x>>16); }

__device__ __forceinline__ void gload_lds16(const u16* g, u16* l){
  __builtin_amdgcn_global_load_lds((const __attribute__((address_space(1))) void*)g,
                                   (__attribute__((address_space(3))) void*)l, 16, 0, 0);
}

// ---------------- sentinel ----------------
__global__ void k_fail(float* out){ int t=threadIdx.x; if(t<128) out[t]=2.0f; }

// ---------------- batched edge-CSR counts ----------------
__global__ void k_counte3(const int* __restrict__ d0, const int* __restrict__ d1, const int* __restrict__ d2,
                          int* __restrict__ c0, int* __restrict__ c1, int* __restrict__ c2){
  int z = blockIdx.z;
  const int* d = z==0? d0 : z==1? d1 : d2;
  int* c = z==0? c0 : z==1? c1 : c2;
  int E = z==0? EFULL : EPAR;
  int e = blockIdx.x*256 + threadIdx.x;
  if (e < E) atomicAdd(&c[d[e]], 1);
}

__global__ void k_scan3(const int* __restrict__ c0, const int* __restrict__ c1, const int* __restrict__ c2,
                        int* __restrict__ r0, int* __restrict__ r1, int* __restrict__ r2,
                        int* __restrict__ w0, int* __restrict__ w1, int* __restrict__ w2){
  __shared__ int sums[1024];
  int z = blockIdx.x;
  const int* cnt = z==0? c0 : z==1? c1 : c2;
  int* rp = z==0? r0 : z==1? r1 : r2;
  int* wp = z==0? w0 : z==1? w1 : w2;
  int t = threadIdx.x;
  const int CH = (NN + 1023)/1024;
  int c00 = t*CH;
  int s = 0;
  for (int i=0;i<CH;i++){ int idx=c00+i; s += (idx<NN)? cnt[idx] : 0; }
  sums[t] = s; __syncthreads();
  for (int off=1; off<1024; off<<=1){
    int v = (t>=off)? sums[t-off] : 0;
    __syncthreads();
    sums[t] += v;
    __syncthreads();
  }
  int run = (t==0)? 0 : sums[t-1];
  for (int i=0;i<CH;i++){
    int idx=c00+i;
    if (idx<NN){ rp[idx]=run; wp[idx]=run; run += cnt[idx]; }
  }
  if (t==1023) rp[NN] = sums[1023];
}

// ---------------- batched 64-bin counts ----------------
__global__ void k_count64(const int* __restrict__ rt0, const int* __restrict__ rt1,
                          const int* __restrict__ d0, const int* __restrict__ d1,
                          int* __restrict__ c0, int* __restrict__ c1,
                          int* __restrict__ c2, int* __restrict__ c3){
  int z = blockIdx.z;
  int i = blockIdx.x*256 + threadIdx.x;
  if (i >= NN) return;
  if      (z==0) atomicAdd(&c0[rt0[i]], 1);
  else if (z==1) atomicAdd(&c1[rt1[i]], 1);
  else if (z==2) atomicAdd(&c2[rt0[d0[i]]], 1);
  else           atomicAdd(&c3[rt1[d1[i]]], 1);
}

__global__ void k_scan64x4(const int* __restrict__ c0, const int* __restrict__ c1,
                           const int* __restrict__ c2, const int* __restrict__ c3,
                           int* __restrict__ r0, int* __restrict__ r1,
                           int* __restrict__ r2, int* __restrict__ r3,
                           int* __restrict__ w2, int* __restrict__ w3){
  int t = threadIdx.x;
  if (t >= 4) return;
  const int* c = t==0?c0:t==1?c1:t==2?c2:c3;
  int* r = t==0?r0:t==1?r1:t==2?r2:r3;
  int run=0;
  for (int i=0;i<64;i++){
    r[i]=run;
    if (t==2) w2[i]=run;
    if (t==3) w3[i]=run;
    run+=c[i];
  }
  r[64]=run;
}

// ---- merged fills; CSR-ordered src/ea stored directly to kill gather chains ----
// z=0: full-graph CSR (src/ea only)   z=1,2: parent CSR (+edge ids)
// z=3,4: route-edge CSR (edge id + src)   z=5,6: nre
__global__ void k_fill_all(
    const int* __restrict__ eiF, const float* __restrict__ eaF,
    const int* __restrict__ ei1, const float* __restrict__ ea1,
    const int* __restrict__ ei2, const float* __restrict__ ea2,
    int* __restrict__ wF, int* __restrict__ wA, int* __restrict__ wB,
    int* __restrict__ srcF, float* __restrict__ eaxF,
    int* __restrict__ eix1, int* __restrict__ src1, float* __restrict__ eax1,
    int* __restrict__ eix2, int* __restrict__ src2, float* __restrict__ eax2,
    const int* __restrict__ rt1, const int* __restrict__ rt2,
    int* __restrict__ w64c, int* __restrict__ w64d,
    int* __restrict__ reix1, int* __restrict__ resrc1,
    int* __restrict__ reix2, int* __restrict__ resrc2,
    const int* __restrict__ rp1, const int* __restrict__ rp2,
    int* __restrict__ nre1, int* __restrict__ nre2){
  int z = blockIdx.z;
  int i = blockIdx.x*256 + threadIdx.x;
  if      (z==0){ if (i<EFULL){ int p=atomicAdd(&wF[eiF[EFULL+i]],1); srcF[p]=eiF[i]; eaxF[p]=eaF[i]; } }
  else if (z==1){ if (i<EPAR) { int p=atomicAdd(&wA[ei1[EPAR+i]],1);  eix1[p]=i; src1[p]=ei1[i]; eax1[p]=ea1[i]; } }
  else if (z==2){ if (i<EPAR) { int p=atomicAdd(&wB[ei2[EPAR+i]],1);  eix2[p]=i; src2[p]=ei2[i]; eax2[p]=ea2[i]; } }
  else if (z==3){ if (i<EPAR) { int p=atomicAdd(&w64c[rt1[ei1[EPAR+i]]],1); reix1[p]=i; resrc1[p]=ei1[i]; } }
  else if (z==4){ if (i<EPAR) { int p=atomicAdd(&w64d[rt2[ei2[EPAR+i]]],1); reix2[p]=i; resrc2[p]=ei2[i]; } }
  else if (z==5){ if (i<NN && rp1[i+1]>rp1[i]) atomicAdd(&nre1[rt1[i]],1); }
  else          { if (i<NN && rp2[i+1]>rp2[i]) atomicAdd(&nre2[rt2[i]],1); }
}

// ---------------- layer-1 x@W with W in registers, x staged in LDS ----------------
// grid: (ceil(NN/128), 2 colchunks, 2 halves)
#define NB 128
__global__ __launch_bounds__(256) void k_xw(const float* __restrict__ x,
    const float* __restrict__ Wl, const float* __restrict__ Wr,
    u16* __restrict__ xl, u16* __restrict__ xr){
  __shared__ float xs[NB*16];
  int half = blockIdx.z;
  const float* W = half? Wr : Wl;
  u16* o = half? xr : xl;
  int c = blockIdx.y*256 + threadIdx.x;
  float wreg[16];
  #pragma unroll
  for (int k=0;k<16;k++) wreg[k] = W[k*512+c];
  int n0 = blockIdx.x*NB;
  for (int i=threadIdx.x; i<NB*16; i+=256){
    int n = n0 + (i>>4);
    xs[i] = (n<NN)? x[(size_t)n*16 + (i&15)] : 0.f;
  }
  __syncthreads();
  int nmax = min(NB, NN-n0);
  for (int i=0;i<nmax;i++){
    float a=0.f;
    #pragma unroll
    for (int k=0;k<16;k++) a += xs[i*16+k]*wreg[k];
    o[(size_t)(n0+i)*512+c] = f2b(a);
  }
}

// ---------------- fused layer-1 GAT (per graph): pipelined, chain-free gathers ----------------
__global__ __launch_bounds__(256) void k_gat1f(
    const int* __restrict__ rp, const int* __restrict__ srcx, const float* __restrict__ eax,
    const float* __restrict__ We, const float* __restrict__ att,
    const u16* __restrict__ xl, const u16* __restrict__ xr,
    const float* __restrict__ bias, u16* __restrict__ out){
  int lane = threadIdx.x & 63;
  int n = blockIdx.x*4 + (threadIdx.x>>6);
  if (n >= NN) return;
  int j0 = lane*8;
  float we8[8], at8[8], rv8[8];
  bf16x8 rvv = *(const bf16x8*)(xr + (size_t)n*512 + j0);
  #pragma unroll
  for (int j=0;j<8;j++){ we8[j]=We[j0+j]; at8[j]=att[j0+j]; rv8[j]=b2f((u16)rvv[j]); }
  int r0 = rp[n], r1 = rp[n+1];
  float den = 0.f;
  float acc[8] = {0,0,0,0,0,0,0,0};
  for (int base=r0; base<r1; base+=64){
    int cnt = min(64, r1-base);
    int mysrc=0; float myea=0.f;
    if (lane < cnt){ mysrc = srcx[base+lane]; myea = eax[base+lane]; }
    int scur = __shfl(mysrc, 0);
    float eacur = __shfl(myea, 0);
    bf16x8 rowc = *(const bf16x8*)(xl + (size_t)scur*512 + j0);
    for (int i=0;i<cnt;i++){
      bf16x8 rown = rowc; float ean = 0.f;
      if (i+1 < cnt){
        int sn = __shfl(mysrc, i+1);
        ean = __shfl(myea, i+1);
        rown = *(const bf16x8*)(xl + (size_t)sn*512 + j0);
      }
      float lvf[8];
      float logit = 0.f;
      #pragma unroll
      for (int j=0;j<8;j++){
        lvf[j] = b2f((u16)rowc[j]);
        float v = lvf[j] + rv8[j] + eacur*we8[j];
        v = v>0.f? v : 0.2f*v;
        logit += v*at8[j];
      }
      logit += __shfl_xor(logit,1);
      logit += __shfl_xor(logit,2);
      logit += __shfl_xor(logit,4);
      float a = __expf(logit);
      den += a;
      #pragma unroll
      for (int j=0;j<8;j++) acc[j] += a*lvf[j];
      rowc = rown; eacur = ean;
    }
  }
  float inv = 1.f/(den + 1e-16f);
  #pragma unroll
  for (int j=0;j<8;j++) out[(size_t)n*512 + j0 + j] = f2b(acc[j]*inv + bias[j0+j]);
}

// ---------------- BN stats, batched z=3, coalesced row-band ----------------
__global__ __launch_bounds__(256) void k_bnstats(const u16* __restrict__ P1, const u16* __restrict__ P2,
    const u16* __restrict__ PF, float* __restrict__ s1, float* __restrict__ s2, float* __restrict__ sF){
  int z = blockIdx.y;
  const u16* P = z==0? P1 : z==1? P2 : PF;
  float* st = z==0? s1 : z==1? s2 : sF;
  int t = threadIdx.x;
  const u32* Pu = (const u32*)P;
  int r0 = blockIdx.x*250, r1 = r0+250;
  float a0=0.f,a1=0.f,q0=0.f,q1=0.f;
  for (int r=r0;r<r1;r++){
    u32 v = Pu[(size_t)r*256 + t];
    float a = b2f((u16)(v & 0xffffu));
    float b = b2f((u16)(v >> 16));
    a0+=a; q0+=a*a; a1+=b; q1+=b*b;
  }
  atomicAdd(&st[2*t],       a0);
  atomicAdd(&st[2*t+1],     a1);
  atomicAdd(&st[512+2*t],   q0);
  atomicAdd(&st[512+2*t+1], q1);
}

// ---------------- BN fold prep ----------------
__global__ void k_prep(const float* __restrict__ st1, const float* __restrict__ st2,
                       const float* __restrict__ stF,
                       const float* __restrict__ g, const float* __restrict__ b,
                       float* __restrict__ sc1, float* __restrict__ sh1,
                       float* __restrict__ sc2, float* __restrict__ sh2){
  int k = blockIdx.x*256 + threadIdx.x;
  if (k >= 1024) return;
  const float invN = 1.f/30000.f;
  const float* st = (k<512)? st1 : stF;
  int kk = k & 511;
  float mu = st[kk]*invN;
  float var = st[512+kk]*invN - mu*mu;
  float sc = g[k]*rsqrtf(var + 1e-5f);
  sc1[k] = sc; sh1[k] = b[k] - mu*sc;
  st = (k<512)? st2 : stF;
  mu = st[kk]*invN;
  var = st[512+kk]*invN - mu*mu;
  sc = g[k]*rsqrtf(var + 1e-5f);
  sc2[k] = sc; sh2[k] = b[k] - mu*sc;
}

// ---------------- B pre-transpose + scale + bf16 ----------------
__global__ __launch_bounds__(256) void k_bt(const float* __restrict__ B0, const float* __restrict__ B1,
                                            const float* __restrict__ sc1, const float* __restrict__ sc2,
                                            u16* __restrict__ Bt1, u16* __restrict__ Bt2){
  __shared__ float tile[64][65];
  int bk = blockIdx.x;
  int bn = blockIdx.y;
  int par = blockIdx.z>>1, half = blockIdx.z&1;
  const float* B = half ? B1 : B0;
  const float* sc = par ? sc2 : sc1;
  u16* Bt = par ? Bt2 : Bt1;
  int nb = half*1024;
  for (int i = threadIdx.x; i < 64*64; i += 256){
    int r = i>>6, c = i&63;
    tile[c][r] = B[(size_t)(bk*64+r)*1024 + bn*64 + c] * sc[bk*64+r];
  }
  __syncthreads();
  for (int i = threadIdx.x; i < 64*64; i += 256){
    int r = i>>6, c = i&63;
    Bt[(size_t)(nb + bn*64 + r)*1024 + bk*64 + c] = f2b(tile[r][c]);
  }
}

// ---------------- shiftB ----------------
__global__ void k_shiftb(const float* __restrict__ B0, const float* __restrict__ B1,
                         const float* __restrict__ sh1, const float* __restrict__ sh2,
                         float* __restrict__ sb1, float* __restrict__ sb2){
  int c = blockIdx.x*256 + threadIdx.x;
  const float* sh = blockIdx.y ? sh2 : sh1;
  float* sb = blockIdx.y ? sb2 : sb1;
  const float* B = (c < 1024) ? B0 : B1;
  int cc = c & 1023;
  float s = 0.f;
  for (int k=0;k<1024;k++) s += sh[k]*B[(size_t)k*1024 + cc];
  sb[c] = s;
}

// ---------------- MFMA GEMM (proven round-10 body) ----------------
__global__ __launch_bounds__(256) void k_gemm(const u16* __restrict__ A0, const u16* __restrict__ A1,
    const u16* __restrict__ Bt, u16* __restrict__ C, int M){
  __shared__ u16 As[128*64];
  __shared__ u16 Bs[128*64];
  int lin = blockIdx.y*16 + blockIdx.x;
  int wg  = (lin&7)*470 + (lin>>3);
  int n0 = (wg & 15)*128;
  int m0 = (wg >> 4)*128;
  int t = threadIdx.x;
  int wave = t>>6, lane = t&63;
  int wm = (wave>>1)*64, wn = (wave&1)*64;
  int rr = lane&15, kq = (lane>>4)*8;
  int srow = t>>3;
  int scol = (t&7)*8;
  int ssw  = ((t&7) ^ (srow&7))*8;
  f32x4 acc[4][4];
  #pragma unroll
  for (int m=0;m<4;m++)
    #pragma unroll
    for (int n=0;n<4;n++){ acc[m][n][0]=0.f; acc[m][n][1]=0.f; acc[m][n][2]=0.f; acc[m][n][3]=0.f; }
  for (int k0=0; k0<1024; k0+=64){
    const u16* Ap = (k0 < 512) ? A0 : A1;
    int kc = k0 & 511;
    #pragma unroll
    for (int i=0;i<4;i++){
      int row = i*32 + srow;
      gload_lds16(Ap + (size_t)(m0+row)*512 + kc + ssw, As + row*64 + scol);
    }
    #pragma unroll
    for (int i=0;i<4;i++){
      int row = i*32 + srow;
      gload_lds16(Bt + (size_t)(n0+row)*1024 + k0 + ssw, Bs + row*64 + scol);
    }
    __syncthreads();
    #pragma unroll
    for (int ks=0; ks<2; ks++){
      int pc = ((ks*4 + (lane>>4)) ^ (lane&7))*8;
      bf16x8 af[4], bb[4];
      #pragma unroll
      for (int m=0;m<4;m++) af[m] = *(const bf16x8*)(&As[(wm + m*16 + rr)*64 + pc]);
      #pragma unroll
      for (int n=0;n<4;n++) bb[n] = *(const bf16x8*)(&Bs[(wn + n*16 + rr)*64 + pc]);
      #pragma unroll
      for (int m=0;m<4;m++)
        #pragma unroll
        for (int n=0;n<4;n++)
          acc[m][n] = __builtin_amdgcn_mfma_f32_16x16x32_bf16(af[m], bb[n], acc[m][n], 0, 0, 0);
    }
    __syncthreads();
  }
  int rq = (lane>>4)*4;
  #pragma unroll
  for (int m=0;m<4;m++)
    #pragma unroll
    for (int n=0;n<4;n++)
      #pragma unroll
      for (int j=0;j<4;j++){
        int row = m0 + wm + m*16 + rq + j;
        int col = n0 + wn + n*16 + rr;
        if (row < M) C[(size_t)row*2048 + col] = f2b(acc[m][n][j]);
      }
}

// ---------------- node-centric layer-2 edge pass: chain-free, pipelined ----------------
__global__ __launch_bounds__(256) void k_edge2f(
    const int* __restrict__ rp, const int* __restrict__ eix,
    const int* __restrict__ srcx, const float* __restrict__ eax,
    const float* __restrict__ We, const float* __restrict__ att,
    const u16* __restrict__ CAT, const float* __restrict__ sb,
    float* __restrict__ alpha){
  int lane = threadIdx.x & 63;
  int n = blockIdx.x*4 + (threadIdx.x>>6);
  if (n >= NN) return;
  int j0 = lane*16;
  float rv[16], we16[16], at16[16];
  bf16x8 rr0 = *(const bf16x8*)(CAT + (size_t)n*2048 + 1024 + j0);
  bf16x8 rr1 = *(const bf16x8*)(CAT + (size_t)n*2048 + 1024 + j0 + 8);
  #pragma unroll
  for (int j=0;j<16;j++){
    rv[j] = b2f((u16)((j<8)? rr0[j] : rr1[j-8])) + sb[1024+j0+j] + sb[j0+j];
    we16[j]=We[j0+j]; at16[j]=att[j0+j];
  }
  int e0 = rp[n], e1 = rp[n+1];
  float den = 0.f;
  for (int base=e0; base<e1; base+=64){
    int cnt = min(64, e1-base);
    int myE=0, mysrc=0; float myea=0.f;
    if (lane < cnt){ myE = eix[base+lane]; mysrc = srcx[base+lane]; myea = eax[base+lane]; }
    int scur = __shfl(mysrc, 0);
    float eacur = __shfl(myea, 0);
    bf16x8 l0c = *(const bf16x8*)(CAT + (size_t)scur*2048 + j0);
    bf16x8 l1c = *(const bf16x8*)(CAT + (size_t)scur*2048 + j0 + 8);
    for (int i=0;i<cnt;i++){
      int ecur = __shfl(myE, i);
      bf16x8 l0n = l0c, l1n = l1c; float ean = 0.f;
      if (i+1 < cnt){
        int sn = __shfl(mysrc, i+1);
        ean = __shfl(myea, i+1);
        l0n = *(const bf16x8*)(CAT + (size_t)sn*2048 + j0);
        l1n = *(const bf16x8*)(CAT + (size_t)sn*2048 + j0 + 8);
      }
      float logit = 0.f;
      #pragma unroll
      for (int j=0;j<16;j++){
        float v = b2f((u16)((j<8)? l0c[j] : l1c[j-8])) + rv[j] + eacur*we16[j];
        v = v>0.f? v : 0.2f*v;
        logit += v*at16[j];
      }
      logit += __shfl_xor(logit,1);
      logit += __shfl_xor(logit,2);
      logit += __shfl_xor(logit,4);
      float ex_ = __expf(logit);
      den += ex_;
      if ((lane&7)==0) alpha[(size_t)ecur*8 + (lane>>3)] = ex_;
      l0c = l0n; l1c = l1n; eacur = ean;
    }
  }
  float dh = __shfl(den, (lane&7)*8);
  float inv = 1.f/(dh + 1e-16f);
  for (int base=e0; base<e1; base+=8){
    int idx = base + (lane>>3);
    if (idx < e1){
      int e = eix[idx];
      alpha[(size_t)e*8 + (lane&7)] *= inv;
    }
  }
}

// ---------------- fused layer-2 aggregation + route pooling (edge-centric) ----------------
#define ECH 32
__global__ __launch_bounds__(256) void k_agg2pool(
    const int* __restrict__ rerp, const int* __restrict__ reix, const int* __restrict__ resrc,
    const int* __restrict__ rrp, const int* __restrict__ nre,
    const float* __restrict__ alpha, const u16* __restrict__ CAT,
    const float* __restrict__ b3, const float* __restrict__ sb,
    float* __restrict__ rs){
  int r = blockIdx.x;
  int c = blockIdx.z*256 + threadIdx.x;
  int h = c >> 7;
  int i0 = rerp[r], i1 = rerp[r+1];
  int per = (i1 - i0 + ECH - 1)/ECH;
  int s0 = i0 + blockIdx.y*per;
  int s1 = min(i1, s0 + per);
  float acc = 0.f;
  for (int i=s0;i<s1;i++){
    int e = reix[i];
    int src = resrc[i];
    float a = alpha[(size_t)e*8 + h];
    acc += a * b2f(CAT[(size_t)src*2048 + c]);
  }
  if (blockIdx.y == 0)
    acc += (float)(rrp[r+1]-rrp[r]) * b3[c] + (float)nre[r] * sb[c];
  if (s0 < s1 || blockIdx.y == 0) atomicAdd(&rs[r*1024 + c], acc);
}

// ---------------- fused cumsum + pn BN ----------------
__global__ void k_cumsum_bn(const float* __restrict__ rs1, const float* __restrict__ rs2,
                            const float* __restrict__ g, const float* __restrict__ b,
                            float* __restrict__ h){
  const float* rs = blockIdx.y ? rs2 : rs1;
  int colbase = blockIdx.y ? 2048 : 0;
  int c = blockIdx.x*256 + threadIdx.x;
  float tot = 0.f;
  for (int r=0;r<64;r++) tot += rs[r*1024+c];
  float cs=0.f, s0=0.f,q0=0.f,s1=0.f,q1=0.f;
  for (int r=0;r<64;r++){
    cs += rs[r*1024+c];
    float m = tot - cs;
    s0+=cs; q0+=cs*cs; s1+=m; q1+=m*m;
  }
  float mu0=s0*(1.f/64.f), v0=q0*(1.f/64.f)-mu0*mu0, n0=rsqrtf(v0+1e-5f);
  float mu1=s1*(1.f/64.f), v1=q1*(1.f/64.f)-mu1*mu1, n1=rsqrtf(v1+1e-5f);
  float g0=g[colbase+c],      b0=b[colbase+c];
  float g1=g[colbase+1024+c], b1=b[colbase+1024+c];
  cs = 0.f;
  for (int r=0;r<64;r++){
    cs += rs[r*1024+c];
    float m = tot - cs;
    h[r*4096 + colbase + c]        = (cs-mu0)*n0*g0 + b0;
    h[r*4096 + colbase + 1024 + c] = (m -mu1)*n1*g1 + b1;
  }
}

// ---------------- MLP split-K partials ----------------
#define KC 512
__global__ __launch_bounds__(256) void k_mlp_part(const float* __restrict__ In,
    const float* __restrict__ W, float* __restrict__ PART, int Ci, int Co){
  __shared__ float tin[64*64];
  int c  = blockIdx.x*64 + (threadIdx.x&63);
  int rg = threadIdx.x>>6;
  int k0 = blockIdx.y*KC, k1 = min(Ci, k0+KC);
  float acc[16];
  #pragma unroll
  for (int j=0;j<16;j++) acc[j]=0.f;
  for (int ks=k0; ks<k1; ks+=64){
    int kw = min(64, k1-ks);
    __syncthreads();
    for (int i=threadIdx.x;i<64*64;i+=256){
      int r=i>>6, k=i&63;
      tin[i] = (k<kw)? In[(size_t)r*Ci + ks + k] : 0.f;
    }
    __syncthreads();
    if (c < Co){
      for (int k=0;k<kw;k+=4){
        float4 w4;
        w4.x = W[(size_t)(ks+k  )*Co + c];
        w4.y = W[(size_t)(ks+k+1)*Co + c];
        w4.z = W[(size_t)(ks+k+2)*Co + c];
        w4.w = W[(size_t)(ks+k+3)*Co + c];
        #pragma unroll
        for (int j=0;j<16;j++){
          float4 t4 = *(const float4*)(&tin[(rg*16+j)*64 + k]);
          acc[j] += t4.x*w4.x + t4.y*w4.y + t4.z*w4.z + t4.w*w4.w;
        }
      }
    }
  }
  if (c < Co){
    float* P = PART + (size_t)blockIdx.y*64*Co;
    #pragma unroll
    for (int j=0;j<16;j++)
      P[(size_t)(rg*16+j)*Co + c] = acc[j];
  }
}

__global__ void k_mlp_red(const float* __restrict__ PART, const float* __restrict__ bias,
                          float* __restrict__ Out, int Co, int SK, int act){
  int idx = blockIdx.x*256 + threadIdx.x;
  if (idx >= 64*Co) return;
  int c = idx % Co;
  float s = bias[c];
  for (int sk=0; sk<SK; sk++) s += PART[(size_t)sk*64*Co + idx];
  if (act) s = s>0.f ? s : 0.01f*s;
  Out[idx] = s;
}

// ---------------- fused MLP tail: 256 -> 128 -> 64 -> 32 -> 1 + sigmoid ----------------
__global__ __launch_bounds__(256) void k_mlp_tail(const float* __restrict__ In,
    const float* __restrict__ W5, const float* __restrict__ c5,
    const float* __restrict__ W6, const float* __restrict__ c6,
    const float* __restrict__ W7, const float* __restrict__ c7,
    const float* __restrict__ W8, const float* __restrict__ c8,
    float* __restrict__ out){
  __shared__ float A[64*256];
  __shared__ float B[64*128];
  int t = threadIdx.x;
  for (int i=t;i<64*256;i+=256) A[i] = In[i];
  __syncthreads();
  for (int idx=t; idx<64*128; idx+=256){
    int r=idx>>7, c=idx&127;
    float s=c5[c];
    for (int k=0;k<256;k++) s += A[r*256+k]*W5[k*128+c];
    B[idx] = s>0.f? s : 0.01f*s;
  }
  __syncthreads();
  for (int idx=t; idx<64*64; idx+=256){
    int r=idx>>6, c=idx&63;
    float s=c6[c];
    for (int k=0;k<128;k++) s += B[r*128+k]*W6[k*64+c];
    A[idx] = s>0.f? s : 0.01f*s;
  }
  __syncthreads();
  for (int idx=t; idx<64*32; idx+=256){
    int r=idx>>5, c=idx&31;
    float s=c7[c];
    for (int k=0;k<64;k++) s += A[r*64+k]*W7[k*32+c];
    B[idx] = s>0.f? s : 0.01f*s;
  }
  __syncthreads();
  if (t<64){
    float s=c8[0];
    for (int k=0;k<32;k++) s += B[t*32+k]*W8[k];
    out[t] = 1.f/(1.f + __expf(-s));
    out[64+t] = 0.f;
  }
}

extern "C" void kernel_launch(void* const* d_in, const int* in_sizes, int n_in,
                              void* d_out, int out_size, void* d_ws, size_t ws_size,
                              hipStream_t stream)
{
  const float* x_p1   = (const float*)d_in[0];
  const float* x_p2   = (const float*)d_in[1];
  const float* x_full = (const float*)d_in[2];
  const float* ea_p1  = (const float*)d_in[3];
  const float* ea_p2  = (const float*)d_in[4];
  const float* ea_full= (const float*)d_in[5];
  const int* ei_p1  = (const int*)d_in[6];
  const int* ei_p2  = (const int*)d_in[7];
  const int* ei_full= (const int*)d_in[8];
  const int* route_p1 = (const int*)d_in[9];
  const int* route_p2 = (const int*)d_in[10];
  const float *Wl1=(const float*)d_in[11], *Wr1=(const float*)d_in[12], *We1=(const float*)d_in[13], *att1=(const float*)d_in[14], *b1=(const float*)d_in[15];
  const float *Wl2=(const float*)d_in[16], *Wr2=(const float*)d_in[17], *We2=(const float*)d_in[18], *att2=(const float*)d_in[19], *b2=(const float*)d_in[20];
  const float *Wl3=(const float*)d_in[21], *Wr3=(const float*)d_in[22], *We3=(const float*)d_in[23], *att3=(const float*)d_in[24], *b3=(const float*)d_in[25];
  const float *bng=(const float*)d_in[26], *bnb=(const float*)d_in[27], *png=(const float*)d_in[28], *pnb=(const float*)d_in[29];
  const float *W[8], *Cb[8];
  for (int i=0;i<8;i++){ W[i]=(const float*)d_in[30+2*i]; Cb[i]=(const float*)d_in[31+2*i]; }

  char* w = (char*)d_ws;
  size_t off = 0;
  auto alloc = [&](size_t bytes)->char*{ char* p = w + off; off += (bytes + 255) & ~(size_t)255; return p; };
  u16* P1bf = (u16*)alloc((size_t)NNP*512*2);
  u16* P2bf = (u16*)alloc((size_t)NNP*512*2);
  u16* FGbf = (u16*)alloc((size_t)NNP*512*2);
  char* BIG = alloc((size_t)NN*2048*2);           // phase1: XL|XR (per graph)  phase3: CAT
  u16*   XLbf = (u16*)BIG;
  u16*   XRbf = (u16*)(BIG + (size_t)NN*512*2);
  u16*   CATbf= (u16*)BIG;
  u16*   Bt1  = (u16*)alloc((size_t)2048*1024*2);
  u16*   Bt2  = (u16*)alloc((size_t)2048*1024*2);
  float* ALPHA=(float*)alloc((size_t)EPAR*8*4);
  float* st1 = (float*)alloc(1024*4);
  float* st2 = (float*)alloc(1024*4);
  float* stF = (float*)alloc(1024*4);
  float* rs1 = (float*)alloc(64*1024*4);
  float* rs2 = (float*)alloc(64*1024*4);
  float* sc1 = (float*)alloc(1024*4);
  float* sh1 = (float*)alloc(1024*4);
  float* sc2 = (float*)alloc(1024*4);
  float* sh2 = (float*)alloc(1024*4);
  float* sb1 = (float*)alloc(2048*4);
  float* sb2 = (float*)alloc(2048*4);
  float* H0  = (float*)alloc(64*4096*4);
  float* H1  = (float*)alloc(64*4096*4);
  float* PART= (float*)alloc((size_t)8*64*2048*4);
  char* cnt_base = alloc(0);
  int* cntF = (int*)alloc(NN*4);
  int* cntA = (int*)alloc(NN*4);
  int* cntB = (int*)alloc(NN*4);
  int* c64a = (int*)alloc(64*4);
  int* c64b = (int*)alloc(64*4);
  int* c64c = (int*)alloc(64*4);
  int* c64d = (int*)alloc(64*4);
  int* nre1 = (int*)alloc(64*4);
  int* nre2 = (int*)alloc(64*4);
  size_t cnt_bytes = (size_t)((char*)alloc(0) - cnt_base);
  int* wpF = (int*)alloc(NN*4);
  int* wpA = (int*)alloc(NN*4);
  int* wpB = (int*)alloc(NN*4);
  int* w64c= (int*)alloc(64*4);
  int* w64d= (int*)alloc(64*4);
  int* rpF = (int*)alloc((NN+1)*4);
  int* rp1 = (int*)alloc((NN+1)*4);
  int* rp2 = (int*)alloc((NN+1)*4);
  int*   srcF = (int*)alloc((size_t)EFULL*4);
  float* eaxF = (float*)alloc((size_t)EFULL*4);
  int*   eix1 = (int*)alloc((size_t)EPAR*4);
  int*   src1 = (int*)alloc((size_t)EPAR*4);
  float* eax1 = (float*)alloc((size_t)EPAR*4);
  int*   eix2 = (int*)alloc((size_t)EPAR*4);
  int*   src2 = (int*)alloc((size_t)EPAR*4);
  float* eax2 = (float*)alloc((size_t)EPAR*4);
  int* rr1 = (int*)alloc(65*4);
  int* rr2 = (int*)alloc(65*4);
  int* rerp1=(int*)alloc(65*4);
  int* rerp2=(int*)alloc(65*4);
  int* reix1=(int*)alloc((size_t)EPAR*4);
  int* resrc1=(int*)alloc((size_t)EPAR*4);
  int* reix2=(int*)alloc((size_t)EPAR*4);
  int* resrc2=(int*)alloc((size_t)EPAR*4);
  if (ws_size < off){ k_fail<<<1,128,0,stream>>>((float*)d_out); return; }

  // ---- zero counters (1 memset) + stats/rs (1 memset) ----
  hipMemsetAsync(cnt_base, 0, cnt_bytes, stream);
  hipMemsetAsync(st1, 0, (size_t)((char*)rs2 - (char*)st1) + 64*1024*4, stream);

  // ---- batched CSR builds ----
  k_counte3<<<dim3((EFULL+255)/256,1,3), 256, 0, stream>>>(ei_full+EFULL, ei_p1+EPAR, ei_p2+EPAR,
                                                           cntF, cntA, cntB);
  k_count64<<<dim3((NN+255)/256,1,4), 256, 0, stream>>>(route_p1, route_p2, ei_p1+EPAR, ei_p2+EPAR,
                                                        c64a, c64b, c64c, c64d);
  k_scan3  <<<3, 1024, 0, stream>>>(cntF, cntA, cntB, rpF, rp1, rp2, wpF, wpA, wpB);
  k_scan64x4<<<1, 64, 0, stream>>>(c64a,c64b,c64c,c64d, rr1,rr2,rerp1,rerp2, w64c,w64d);
  k_fill_all<<<dim3((EFULL+255)/256,1,7), 256, 0, stream>>>(
      ei_full, ea_full, ei_p1, ea_p1, ei_p2, ea_p2,
      wpF, wpA, wpB,
      srcF, eaxF, eix1, src1, eax1, eix2, src2, eax2,
      route_p1, route_p2, w64c, w64d,
      reix1, resrc1, reix2, resrc2,
      rp1, rp2, nre1, nre2);

  // ---- layer-1 GAT: per graph (XL/XR share BIG) ----
  auto gat1 = [&](const float* x, const int* rp, const int* srcx, const float* eax,
                  const float* Wl, const float* Wr, const float* We, const float* att,
                  const float* bias, u16* out){
    k_xw   <<<dim3((NN+NB-1)/NB, 2, 2), 256, 0, stream>>>(x, Wl, Wr, XLbf, XRbf);
    k_gat1f<<<(NN+3)/4, 256, 0, stream>>>(rp, srcx, eax, We, att, XLbf, XRbf, bias, out);
  };
  gat1(x_full, rpF, srcF, eaxF, Wl2, Wr2, We2, att2, b2, FGbf);
  gat1(x_p1,   rp1, src1, eax1, Wl1, Wr1, We1, att1, b1, P1bf);
  gat1(x_p2,   rp2, src2, eax2, Wl1, Wr1, We1, att1, b1, P2bf);

  // ---- BN stats + fold into GEMM B ----
  k_bnstats<<<dim3(120,3), 256, 0, stream>>>(P1bf, P2bf, FGbf, st1, st2, stF);
  k_prep   <<<4, 256, 0, stream>>>(st1, st2, stF, bng, bnb, sc1, sh1, sc2, sh2);
  k_bt     <<<dim3(16,16,4), 256, 0, stream>>>(Wl3, Wr3, sc1, sc2, Bt1, Bt2);
  k_shiftb <<<dim3(8,2), 256, 0, stream>>>(Wl3, Wr3, sh1, sh2, sb1, sb2);

  // ---- layer-2 GAT + fused route pooling, per parent ----
  auto layer2 = [&](const u16* Pbf, const u16* Bt, const float* sb,
                    const int* rp, const int* eix, const int* srcx, const float* eax,
                    const int* rrp, const int* nre, const int* rerp,
                    const int* reix, const int* resrc, float* rs){
    k_gemm <<<dim3(16, (NN+127)/128), 256, 0, stream>>>(Pbf, FGbf, Bt, CATbf, NN);
    k_edge2f<<<(NN+3)/4, 256, 0, stream>>>(rp, eix, srcx, eax, We3, att3, CATbf, sb, ALPHA);
    k_agg2pool<<<dim3(64,ECH,4), 256, 0, stream>>>(rerp, reix, resrc, rrp, nre, ALPHA, CATbf, b3, sb, rs);
  };
  layer2(P1bf, Bt1, sb1, rp1, eix1, src1, eax1, rr1, nre1, rerp1, reix1, resrc1, rs1);
  layer2(P2bf, Bt2, sb2, rp2, eix2, src2, eax2, rr2, nre2, rerp2, reix2, resrc2, rs2);

  // ---- fused cumsum + pn BN -> H0 ----
  k_cumsum_bn<<<dim3(4,2), 256, 0, stream>>>(rs1, rs2, png, pnb, H0);

  // ---- MLP: layers 1-4 split-K, tail fused ----
  int dims[5] = {4096, 2048, 1024, 512, 256};
  float* bufs[2] = {H0, H1};
  for (int i=0;i<4;i++){
    int Ci = dims[i], Co = dims[i+1];
    int SK = (Ci + KC - 1)/KC;
    k_mlp_part<<<dim3((Co+63)/64, SK), 256, 0, stream>>>(bufs[i&1], W[i], PART, Ci, Co);
    k_mlp_red <<<(64*Co+255)/256, 256, 0, stream>>>(PART, Cb[i], bufs[(i+1)&1], Co, SK, 1);
  }
  k_mlp_tail<<<1, 256, 0, stream>>>(H0, W[4], Cb[4], W[5], Cb[5], W[6], Cb[6], W[7], Cb[7],
                                    (float*)d_out);
}